// Round 2
// 789.073 us; speedup vs baseline: 1.3171x; 1.3171x over previous
//
#include <hip/hip_runtime.h>
#include <cstddef>

#define BB 8
#define TT 128
#define NN 256
#define DD 64

typedef _Float16 half2_t __attribute__((ext_vector_type(2)));
typedef _Float16 half4_t __attribute__((ext_vector_type(4)));
typedef _Float16 half8_t __attribute__((ext_vector_type(8)));
typedef float f32x4 __attribute__((ext_vector_type(4)));

#if defined(__has_builtin)
#  if __has_builtin(__builtin_amdgcn_fdot2)
#    define FDOT2(a,b,c) __builtin_amdgcn_fdot2((a),(b),(c),false)
#  endif
#endif
#ifndef FDOT2
#  define FDOT2(a,b,c) ((c) + (float)(a).x*(float)(b).x + (float)(a).y*(float)(b).y)
#endif

union h8u { half8_t v; half2_t h[4]; };

// ---------------- K0: pack W matrices to half2 in ws ----------------
__global__ __launch_bounds__(256) void k_prep(
    const float* __restrict__ Wq, const float* __restrict__ Wk, const float* __restrict__ Wv,
    unsigned int* __restrict__ wq2, unsigned int* __restrict__ wk2, unsigned int* __restrict__ wv2)
{
  int t = blockIdx.x * 256 + threadIdx.x;
  if (t < 2048) {
    half2_t a; a.x = (_Float16)Wq[2*t]; a.y = (_Float16)Wq[2*t+1];
    wq2[t] = __builtin_bit_cast(unsigned int, a);
    half2_t b; b.x = (_Float16)Wk[2*t]; b.y = (_Float16)Wk[2*t+1];
    wk2[t] = __builtin_bit_cast(unsigned int, b);
    half2_t c; c.x = (_Float16)Wv[2*t]; c.y = (_Float16)Wv[2*t+1];
    wv2[t] = __builtin_bit_cast(unsigned int, c);
  }
}

// ---------------- K1: MFMA fused QKV + per-(b,n) temporal attention ----------------
// One block = one (b,n). 256 threads = 4 waves; wave w owns i-rows [32w, 32w+32).
// mfma_f32_16x16x32_f16 layouts:
//   A: row m = l&15,  k = 8*(l>>4)+j   (8 f16/lane)
//   B: col n = l&15,  k = 8*(l>>4)+j
//   C/D: col = l&15,  row = 4*(l>>4)+r (4 f32/lane)
#define KSTR 72    // sK row stride (f16): 144B -> lane stride ≡ 4 banks (2-way, free)
#define PSTR 136   // sVt / sP row stride (f16): 272B -> same property

__device__ __forceinline__ half8_t wfrag(const unsigned int* __restrict__ W2, int e, int k0) {
  // W2 is half2-packed row-major [64][32 dwords]; frag = W[e][k0..k0+7] (16B aligned)
  return *(const half8_t*)(W2 + e * 32 + (k0 >> 1));
}

__global__ __launch_bounds__(256, 2) void k_attn(
    const float* __restrict__ Hi, const float* __restrict__ Hj,
    const unsigned int* __restrict__ wq2, const unsigned int* __restrict__ wk2,
    const unsigned int* __restrict__ wv2,
    const float* __restrict__ bq, const float* __restrict__ bk, const float* __restrict__ bv,
    const float* __restrict__ lgp, const float* __restrict__ ltp,
    float* __restrict__ out)
{
  __shared__ __align__(16) _Float16 sK[TT][KSTR];       // K rows [j][d]      18432 B
  __shared__ __align__(16) _Float16 sVt[DD][PSTR];      // V^T   [e][j]       17408 B
  __shared__ __align__(16) _Float16 sP[4][32][PSTR];    // per-wave Q then P  34816 B
  __shared__ float sDecay[TT];                          //                      512 B

  const int b   = blockIdx.x >> 8;
  const int n   = blockIdx.x & 255;
  const int tid = threadIdx.x;
  const int w   = tid >> 6;
  const int l   = tid & 63;
  const int l16 = l & 15;
  const int lg4 = l >> 4;

  const float gamma = fmaxf(__expf(lgp[0]), 0.01f);
  const float tau   = fmaxf(__expf(ltp[0]), 0.01f);
  const float scale = 1.0f / (8.0f * tau);
  if (tid < TT) {
    float dt = gamma * (float)tid * (1.0f / 127.0f);
    sDecay[tid] = __logf(__expf(-dt) + 1e-8f);
  }

  // ---- A-fragments of Hi/Hj rows (each row read exactly once per input) ----
  const int row0 = 32 * w;
  half8_t hai[2][2], haj[2][2];
  #pragma unroll
  for (int mt = 0; mt < 2; mt++) {
    const int i = row0 + 16 * mt + l16;
    const float* ri = Hi + (((size_t)b * TT + i) * NN + n) * DD;
    const float* rj = Hj + (((size_t)b * TT + i) * NN + n) * DD;
    #pragma unroll
    for (int ks = 0; ks < 2; ks++) {
      const int k0 = 32 * ks + 8 * lg4;
      float4 a = *(const float4*)(ri + k0);
      float4 c = *(const float4*)(ri + k0 + 4);
      half8_t h;
      h[0]=(_Float16)a.x; h[1]=(_Float16)a.y; h[2]=(_Float16)a.z; h[3]=(_Float16)a.w;
      h[4]=(_Float16)c.x; h[5]=(_Float16)c.y; h[6]=(_Float16)c.z; h[7]=(_Float16)c.w;
      hai[mt][ks] = h;
      a = *(const float4*)(rj + k0);
      c = *(const float4*)(rj + k0 + 4);
      h[0]=(_Float16)a.x; h[1]=(_Float16)a.y; h[2]=(_Float16)a.z; h[3]=(_Float16)a.w;
      h[4]=(_Float16)c.x; h[5]=(_Float16)c.y; h[6]=(_Float16)c.z; h[7]=(_Float16)c.w;
      haj[mt][ks] = h;
    }
  }

  // ---- Q = (Hi @ Wq^T + bq) * scale -> sP[w] rows [i_local][e] (f16) ----
  #pragma unroll
  for (int nt = 0; nt < 4; nt++) {
    const int e = 16 * nt + l16;
    half8_t wb0 = wfrag(wq2, e, 8 * lg4);
    half8_t wb1 = wfrag(wq2, e, 32 + 8 * lg4);
    const float be = bq[e];
    #pragma unroll
    for (int mt = 0; mt < 2; mt++) {
      f32x4 acc = {be, be, be, be};
      acc = __builtin_amdgcn_mfma_f32_16x16x32_f16(hai[mt][0], wb0, acc, 0, 0, 0);
      acc = __builtin_amdgcn_mfma_f32_16x16x32_f16(hai[mt][1], wb1, acc, 0, 0, 0);
      #pragma unroll
      for (int r = 0; r < 4; r++)
        sP[w][16 * mt + 4 * lg4 + r][e] = (_Float16)(acc[r] * scale);
    }
  }

  // ---- K = Hj @ Wk^T + bk -> sK rows [j][d] (f16) ----
  #pragma unroll
  for (int nt = 0; nt < 4; nt++) {
    const int e = 16 * nt + l16;
    half8_t wb0 = wfrag(wk2, e, 8 * lg4);
    half8_t wb1 = wfrag(wk2, e, 32 + 8 * lg4);
    const float be = bk[e];
    #pragma unroll
    for (int mt = 0; mt < 2; mt++) {
      f32x4 acc = {be, be, be, be};
      acc = __builtin_amdgcn_mfma_f32_16x16x32_f16(haj[mt][0], wb0, acc, 0, 0, 0);
      acc = __builtin_amdgcn_mfma_f32_16x16x32_f16(haj[mt][1], wb1, acc, 0, 0, 0);
      #pragma unroll
      for (int r = 0; r < 4; r++)
        sK[row0 + 16 * mt + 4 * lg4 + r][e] = (_Float16)acc[r];
    }
  }

  // ---- V = Hj @ Wv^T + bv -> sVt[e][j] (transposed, packed 4-j ds_write_b64) ----
  #pragma unroll
  for (int nt = 0; nt < 4; nt++) {
    const int e = 16 * nt + l16;
    half8_t wb0 = wfrag(wv2, e, 8 * lg4);
    half8_t wb1 = wfrag(wv2, e, 32 + 8 * lg4);
    const float be = bv[e];
    #pragma unroll
    for (int mt = 0; mt < 2; mt++) {
      f32x4 acc = {be, be, be, be};
      acc = __builtin_amdgcn_mfma_f32_16x16x32_f16(haj[mt][0], wb0, acc, 0, 0, 0);
      acc = __builtin_amdgcn_mfma_f32_16x16x32_f16(haj[mt][1], wb1, acc, 0, 0, 0);
      const int jb = row0 + 16 * mt + 4 * lg4;
      half4_t v4;
      v4[0] = (_Float16)acc[0]; v4[1] = (_Float16)acc[1];
      v4[2] = (_Float16)acc[2]; v4[3] = (_Float16)acc[3];
      *(half4_t*)(&sVt[e][jb]) = v4;
    }
  }
  __syncthreads();

  // ---- load Q A-frags from own strip (before overwriting it with P) ----
  half8_t qa[2][2];
  #pragma unroll
  for (int mt = 0; mt < 2; mt++)
    #pragma unroll
    for (int ks = 0; ks < 2; ks++)
      qa[mt][ks] = *(const half8_t*)(&sP[w][16 * mt + l16][32 * ks + 8 * lg4]);

  // ---- S = Q K^T + decay; P = exp(S); rowsum; P -> sP[w] (f16) ----
  float rs[2][4] = {{0.f,0.f,0.f,0.f},{0.f,0.f,0.f,0.f}};
  for (int jt = 0; jt < 8; jt++) {
    const int j = 16 * jt + l16;
    half8_t kb0 = *(const half8_t*)(&sK[j][8 * lg4]);
    half8_t kb1 = *(const half8_t*)(&sK[j][32 + 8 * lg4]);
    #pragma unroll
    for (int mt = 0; mt < 2; mt++) {
      f32x4 acc = {0.f, 0.f, 0.f, 0.f};
      acc = __builtin_amdgcn_mfma_f32_16x16x32_f16(qa[mt][0], kb0, acc, 0, 0, 0);
      acc = __builtin_amdgcn_mfma_f32_16x16x32_f16(qa[mt][1], kb1, acc, 0, 0, 0);
      #pragma unroll
      for (int r = 0; r < 4; r++) {
        const int il = 16 * mt + 4 * lg4 + r;
        int di = (row0 + il) - j; di = di < 0 ? -di : di;
        float p = __expf(acc[r] + sDecay[di]);
        rs[mt][r] += p;
        sP[w][il][j] = (_Float16)p;
      }
    }
  }

  // ---- O = P V ----
  f32x4 oacc[2][4] = {};
  #pragma unroll
  for (int ks = 0; ks < 4; ks++) {
    const int j0 = 32 * ks + 8 * lg4;
    half8_t pa0 = *(const half8_t*)(&sP[w][l16][j0]);
    half8_t pa1 = *(const half8_t*)(&sP[w][16 + l16][j0]);
    #pragma unroll
    for (int nt = 0; nt < 4; nt++) {
      half8_t vb = *(const half8_t*)(&sVt[16 * nt + l16][j0]);
      oacc[0][nt] = __builtin_amdgcn_mfma_f32_16x16x32_f16(pa0, vb, oacc[0][nt], 0, 0, 0);
      oacc[1][nt] = __builtin_amdgcn_mfma_f32_16x16x32_f16(pa1, vb, oacc[1][nt], 0, 0, 0);
    }
  }

  // ---- rowsum reduce across the 16-lane col groups; scale + store ----
  #pragma unroll
  for (int mt = 0; mt < 2; mt++)
    #pragma unroll
    for (int r = 0; r < 4; r++) {
      float v = rs[mt][r];
      v += __shfl_xor(v, 1, 64);
      v += __shfl_xor(v, 2, 64);
      v += __shfl_xor(v, 4, 64);
      v += __shfl_xor(v, 8, 64);
      rs[mt][r] = 1.0f / v;
    }
  #pragma unroll
  for (int mt = 0; mt < 2; mt++) {
    #pragma unroll
    for (int r = 0; r < 4; r++) {
      const int i = row0 + 16 * mt + 4 * lg4 + r;
      float* orow = out + (((size_t)b * TT + i) * NN + n) * DD;
      const float rl = rs[mt][r];
      #pragma unroll
      for (int nt = 0; nt < 4; nt++)
        orow[16 * nt + l16] = oacc[mt][nt][r] * rl;
    }
  }
}

// ---------------- K2: adjacency adpT[n][m] = softmax_row_m(relu(e1@e2)) ----------------
__global__ __launch_bounds__(256) void k_adp(
    const float* __restrict__ e1, const float* __restrict__ e2,
    float* __restrict__ adpT)
{
  const int m = blockIdx.x, n = threadIdx.x;
  float s = 0.f;
  #pragma unroll
  for (int k = 0; k < 32; k++) s += e1[m*32+k] * e2[k*256+n];
  s = fmaxf(s, 0.f);
  __shared__ float red[256];
  red[n] = s; __syncthreads();
  for (int off = 128; off > 0; off >>= 1) {
    if (n < off) red[n] = fmaxf(red[n], red[n+off]);
    __syncthreads();
  }
  float mx = red[0];
  __syncthreads();
  float p = __expf(s - mx);
  red[n] = p; __syncthreads();
  for (int off = 128; off > 0; off >>= 1) {
    if (n < off) red[n] += red[n+off];
    __syncthreads();
  }
  adpT[n*256 + m] = p / red[0];
}

// ---------------- K3: GCN + residual + LN1 (in-place on x) ----------------
__global__ __launch_bounds__(256) void k_gcn(
    float* __restrict__ x, const float* __restrict__ adpT,
    const float* __restrict__ Wg, const float* __restrict__ bg,
    const float* __restrict__ g1, const float* __restrict__ b1)
{
  __shared__ float sx[NN][DD];  // 64KB
  float* tile = x + (size_t)blockIdx.x * NN * DD;
  for (int idx = threadIdx.x; idx < NN * DD; idx += 256)
    sx[idx >> 6][idx & 63] = tile[idx];
  __syncthreads();

  const int m = threadIdx.x;
  float g[DD];
  #pragma unroll
  for (int d = 0; d < DD; d++) g[d] = 0.f;
  for (int n = 0; n < NN; n++) {
    float a = adpT[n * 256 + m];
    const float4* r = (const float4*)sx[n];
    #pragma unroll
    for (int dq = 0; dq < 16; dq++) {
      float4 v = r[dq];
      g[4*dq]   += a * v.x; g[4*dq+1] += a * v.y;
      g[4*dq+2] += a * v.z; g[4*dq+3] += a * v.w;
    }
  }
  float y[DD]; float s1 = 0.f;
  #pragma unroll
  for (int e = 0; e < DD; e++) {
    float h = bg[e];
    const float4* w = (const float4*)(Wg + e * DD);
    #pragma unroll
    for (int dq = 0; dq < 16; dq++) {
      float4 wv = w[dq];
      h += g[4*dq]*wv.x + g[4*dq+1]*wv.y + g[4*dq+2]*wv.z + g[4*dq+3]*wv.w;
    }
    h = fmaxf(h, 0.f);
    float yv = sx[m][e] + h;
    y[e] = yv; s1 += yv;
  }
  float mean = s1 * (1.f/64.f);
  float s2 = 0.f;
  #pragma unroll
  for (int e = 0; e < DD; e++) { float d0 = y[e] - mean; s2 += d0 * d0; }
  float rstd = rsqrtf(s2 * (1.f/64.f) + 1e-5f);
  float* orow = tile + m * DD;
  #pragma unroll
  for (int e = 0; e < DD; e++) orow[e] = (y[e] - mean) * rstd * g1[e] + b1[e];
}

// ---------------- K3b: GI[t][seq][192] = x_ln1 @ Wih^T + bih  (fp16, parallel) ----------
__global__ __launch_bounds__(256) void k_gih(
    const float* __restrict__ x, const float* __restrict__ Wih,
    const float* __restrict__ bih, unsigned int* __restrict__ GI2)
{
  __shared__ unsigned int sW[192*32];   // 24KB packed half2 weights
  __shared__ unsigned int sbuf[256*33]; // overlay: x-stage [256][33], then out-stage [256][25]
  const int tid = threadIdx.x;
  const int b = blockIdx.x >> 7, t = blockIdx.x & 127;
  const float* xt = x + (((size_t)b * TT + t) * NN) * DD;

  for (int idx = tid; idx < 192*32; idx += 256) {
    float2 w = ((const float2*)Wih)[idx];
    half2_t h; h.x = (_Float16)w.x; h.y = (_Float16)w.y;
    sW[idx] = __builtin_bit_cast(unsigned int, h);
  }
  for (int idx = tid; idx < 256*32; idx += 256) {
    int n = idx >> 5, k = idx & 31;
    float2 v = ((const float2*)xt)[idx];
    half2_t h; h.x = (_Float16)v.x; h.y = (_Float16)v.y;
    sbuf[n*33 + k] = __builtin_bit_cast(unsigned int, h);
  }
  __syncthreads();
  half2_t xr[32];
  #pragma unroll
  for (int k = 0; k < 32; k++) xr[k] = __builtin_bit_cast(half2_t, sbuf[tid*33 + k]);
  __syncthreads();

  const size_t blockbase = ((size_t)t * 2048 + b * 256) * 96;  // dword index
  for (int c = 0; c < 4; c++) {
    #pragma unroll 2
    for (int j2 = 0; j2 < 24; j2++) {
      int e0 = c*48 + 2*j2;
      float a0 = bih[e0], a1 = bih[e0+1];
      const half8_t* w0 = (const half8_t*)(sW + e0*32);
      const half8_t* w1 = (const half8_t*)(sW + (e0+1)*32);
      #pragma unroll
      for (int kq = 0; kq < 8; kq++) {
        h8u ua, ub; ua.v = w0[kq]; ub.v = w1[kq];
        #pragma unroll
        for (int m = 0; m < 4; m++) {
          a0 = FDOT2(ua.h[m], xr[4*kq+m], a0);
          a1 = FDOT2(ub.h[m], xr[4*kq+m], a1);
        }
      }
      half2_t o; o.x = (_Float16)a0; o.y = (_Float16)a1;
      sbuf[tid*25 + j2] = __builtin_bit_cast(unsigned int, o);
    }
    __syncthreads();
    for (int idx = tid; idx < 6144; idx += 256) {
      int n = idx / 24, e2 = idx % 24;
      GI2[blockbase + (size_t)n*96 + c*24 + e2] = sbuf[n*25 + e2];
    }
    __syncthreads();
  }
}

// ---------------- K4: GRU over T (gi precomputed) + LN2 + residual ----------------
__global__ __launch_bounds__(256) void k_gru_gi(
    float* __restrict__ x, const _Float16* __restrict__ GIh,
    const float* __restrict__ Whh, const float* __restrict__ bhh,
    const float* __restrict__ g2, const float* __restrict__ b2)
{
  __shared__ __align__(16) _Float16 hsh[4*64];
  __shared__ float ghs[4*192];
  const int tid = threadIdx.x;
  const int b = blockIdx.x >> 6, n4 = blockIdx.x & 63;
  const int s = tid >> 6, d = tid & 63;

  half2_t wh[32];
  float bh = 0.f;
  if (tid < 192) {
    bh = bhh[tid];
    const float2* wr = (const float2*)Whh;
    #pragma unroll
    for (int k = 0; k < 32; k++) {
      float2 w = wr[tid*32 + k];
      half2_t h; h.x = (_Float16)w.x; h.y = (_Float16)w.y;
      wh[k] = h;
    }
  }
  hsh[tid] = (_Float16)0.f;
  const float lng = g2[d], lnb = b2[d];
  float hreg = 0.f;
  size_t gioff = ((size_t)b*256 + n4*4 + s)*192 + d;
  size_t xoff  = (((size_t)b * TT) * NN + n4*4 + s)*DD + d;
  __syncthreads();

  for (int t = 0; t < TT; t++) {
    float gir = (float)GIh[gioff];
    float giz = (float)GIh[gioff + 64];
    float gin = (float)GIh[gioff + 128];
    float xv  = x[xoff];

    if (tid < 192) {
      float a0 = bh, a1 = bh, a2 = bh, a3 = bh;
      const half8_t* h8 = (const half8_t*)hsh;
      #pragma unroll
      for (int kq = 0; kq < 8; kq++) {
        h8u u0, u1, u2, u3;
        u0.v = h8[kq]; u1.v = h8[8+kq]; u2.v = h8[16+kq]; u3.v = h8[24+kq];
        #pragma unroll
        for (int m = 0; m < 4; m++) {
          half2_t w = wh[4*kq + m];
          a0 = FDOT2(w, u0.h[m], a0);
          a1 = FDOT2(w, u1.h[m], a1);
          a2 = FDOT2(w, u2.h[m], a2);
          a3 = FDOT2(w, u3.h[m], a3);
        }
      }
      ghs[tid] = a0; ghs[192 + tid] = a1; ghs[384 + tid] = a2; ghs[576 + tid] = a3;
    }
    __syncthreads();

    float rr = gir + ghs[s*192 + d];
    float zz = giz + ghs[s*192 + 64 + d];
    float hn_ = ghs[s*192 + 128 + d];
    float r = 1.f / (1.f + __expf(-rr));
    float z = 1.f / (1.f + __expf(-zz));
    float e = __expf(2.f * (gin + r * hn_));
    float nt = 1.f - 2.f / (e + 1.f);     // tanh, overflow-safe
    float hn = (1.f - z) * nt + z * hreg;
    hreg = hn;

    float yv = xv + hn;
    float s1 = yv, s2v = yv * yv;
    #pragma unroll
    for (int off = 32; off > 0; off >>= 1) {
      s1  += __shfl_xor(s1,  off, 64);
      s2v += __shfl_xor(s2v, off, 64);
    }
    float mean = s1 * 0.015625f;
    float var  = fmaxf(s2v * 0.015625f - mean * mean, 0.f);
    float hm = (yv - mean) * rsqrtf(var + 1e-5f) * lng + lnb;

    x[xoff] = xv + hm;
    hsh[tid] = (_Float16)hn;
    __syncthreads();

    gioff += (size_t)2048 * 192;
    xoff  += (size_t)NN * DD;
  }
}

// ---------------- K4 fallback: original fused GRU (ws too small for GI) ----------------
__global__ __launch_bounds__(256) void k_gru(
    float* __restrict__ x,
    const float* __restrict__ Wih, const float* __restrict__ Whh,
    const float* __restrict__ bih, const float* __restrict__ bhh,
    const float* __restrict__ g2, const float* __restrict__ b2)
{
  __shared__ half2_t sWi[192][33];
  __shared__ half2_t sWh[192][33];
  __shared__ float   xs[4][64];
  __shared__ half2_t xs_h[4][32];
  __shared__ float   hs_f[4][64];
  __shared__ half2_t hs_h[4][32];
  __shared__ float   gis[4][192];
  __shared__ float   ghs[4][192];

  const int b  = blockIdx.x >> 6;
  const int ng = blockIdx.x & 63;

  for (int idx = threadIdx.x; idx < 192 * 32; idx += 256) {
    int g = idx >> 5, dh = idx & 31;
    half2_t hv; hv.x = (_Float16)Wih[g*64 + 2*dh]; hv.y = (_Float16)Wih[g*64 + 2*dh + 1];
    sWi[g][dh] = hv;
    half2_t hw; hw.x = (_Float16)Whh[g*64 + 2*dh]; hw.y = (_Float16)Whh[g*64 + 2*dh + 1];
    sWh[g][dh] = hw;
  }
  const int s_d = threadIdx.x >> 6;
  const int d_d = threadIdx.x & 63;
  hs_f[s_d][d_d] = 0.f;
  ((_Float16*)hs_h[s_d])[d_d] = (_Float16)0.f;
  const float lng = g2[d_d], lnb = b2[d_d];

  int   tsk_s[3], tsk_g[3];
  float tb_i[3], tb_h[3];
  #pragma unroll
  for (int k = 0; k < 3; k++) {
    int task = threadIdx.x + k * 256;
    tsk_s[k] = task / 192; tsk_g[k] = task % 192;
    tb_i[k] = bih[tsk_g[k]]; tb_h[k] = bhh[tsk_g[k]];
  }
  __syncthreads();

  const size_t base = (((size_t)b * TT) * NN + ng * 4) * DD;
  for (int t = 0; t < TT; t++) {
    const size_t row = base + (size_t)t * NN * DD + s_d * 64 + d_d;
    float xv = x[row];
    xs[s_d][d_d] = xv;
    ((_Float16*)xs_h[s_d])[d_d] = (_Float16)xv;
    __syncthreads();

    #pragma unroll
    for (int k = 0; k < 3; k++) {
      int s = tsk_s[k], g = tsk_g[k];
      float ai = tb_i[k], ah = tb_h[k];
      #pragma unroll
      for (int dh = 0; dh < 32; dh++) {
        ai = FDOT2(sWi[g][dh], xs_h[s][dh], ai);
        ah = FDOT2(sWh[g][dh], hs_h[s][dh], ah);
      }
      gis[s][g] = ai; ghs[s][g] = ah;
    }
    __syncthreads();

    float gr = gis[s_d][d_d]      + ghs[s_d][d_d];
    float gz = gis[s_d][64 + d_d] + ghs[s_d][64 + d_d];
    float r  = 1.f / (1.f + __expf(-gr));
    float z  = 1.f / (1.f + __expf(-gz));
    float nn = tanhf(gis[s_d][128 + d_d] + r * ghs[s_d][128 + d_d]);
    float ho = hs_f[s_d][d_d];
    float hn = (1.f - z) * nn + z * ho;

    float yv = xs[s_d][d_d] + hn;
    float s1 = yv, s2 = yv * yv;
    #pragma unroll
    for (int off = 32; off > 0; off >>= 1) {
      s1 += __shfl_xor(s1, off, 64);
      s2 += __shfl_xor(s2, off, 64);
    }
    float mean = s1 * (1.f / 64.f);
    float var  = fmaxf(s2 * (1.f / 64.f) - mean * mean, 0.f);
    float hm = (yv - mean) * rsqrtf(var + 1e-5f) * lng + lnb;

    x[row] = xs[s_d][d_d] + hm;
    hs_f[s_d][d_d] = hn;
    ((_Float16*)hs_h[s_d])[d_d] = (_Float16)hn;
    __syncthreads();
  }
}

extern "C" void kernel_launch(void* const* d_in, const int* in_sizes, int n_in,
                              void* d_out, int out_size, void* d_ws, size_t ws_size,
                              hipStream_t stream) {
  const float* Hi  = (const float*)d_in[0];
  const float* Hj  = (const float*)d_in[1];
  const float* Wq  = (const float*)d_in[2];  const float* bq = (const float*)d_in[3];
  const float* Wk  = (const float*)d_in[4];  const float* bk = (const float*)d_in[5];
  const float* Wv  = (const float*)d_in[6];  const float* bv = (const float*)d_in[7];
  const float* lg  = (const float*)d_in[8];  const float* lt = (const float*)d_in[9];
  const float* e1  = (const float*)d_in[10]; const float* e2 = (const float*)d_in[11];
  const float* Wg  = (const float*)d_in[12]; const float* bg = (const float*)d_in[13];
  const float* g1  = (const float*)d_in[14]; const float* b1 = (const float*)d_in[15];
  const float* Wih = (const float*)d_in[16]; const float* Whh = (const float*)d_in[17];
  const float* bih = (const float*)d_in[18]; const float* bhh = (const float*)d_in[19];
  const float* g2  = (const float*)d_in[20]; const float* b2  = (const float*)d_in[21];
  float* out  = (float*)d_out;

  float* adpT = (float*)d_ws;                          // 256KB @ offset 0
  unsigned int* wq2 = (unsigned int*)d_ws + 65536;     // 3 x 8KB
  unsigned int* wk2 = wq2 + 2048;
  unsigned int* wv2 = wk2 + 2048;
  const size_t gi_off = 286720;                        // byte offset, 512-aligned
  const size_t gi_bytes = (size_t)2048 * TT * 192 * 2; // 96MB fp16
  const bool use_gi = ws_size >= gi_off + gi_bytes;
  unsigned int* GI2 = (unsigned int*)((char*)d_ws + gi_off);
  _Float16*     GIh = (_Float16*)((char*)d_ws + gi_off);

  k_prep<<<dim3(8),     dim3(256), 0, stream>>>(Wq, Wk, Wv, wq2, wk2, wv2);
  k_attn<<<dim3(BB*NN), dim3(256), 0, stream>>>(Hi, Hj, wq2, wk2, wv2, bq, bk, bv, lg, lt, out);
  k_adp <<<dim3(NN),    dim3(256), 0, stream>>>(e1, e2, adpT);
  k_gcn <<<dim3(BB*TT), dim3(256), 0, stream>>>(out, adpT, Wg, bg, g1, b1);
  if (use_gi) {
    k_gih   <<<dim3(BB*TT), dim3(256), 0, stream>>>(out, Wih, bih, GI2);
    k_gru_gi<<<dim3(512),   dim3(256), 0, stream>>>(out, GIh, Whh, bhh, g2, b2);
  } else {
    k_gru   <<<dim3(512),   dim3(256), 0, stream>>>(out, Wih, Whh, bih, bhh, g2, b2);
  }
}

// Round 4
// 559.098 us; speedup vs baseline: 1.8588x; 1.4113x over previous
//
#include <hip/hip_runtime.h>
#include <cstddef>

#define BB 8
#define TT 128
#define NN 256
#define DD 64

typedef _Float16 half2_t __attribute__((ext_vector_type(2)));
typedef _Float16 half4_t __attribute__((ext_vector_type(4)));
typedef _Float16 half8_t __attribute__((ext_vector_type(8)));
typedef float f32x4 __attribute__((ext_vector_type(4)));

#if defined(__has_builtin)
#  if __has_builtin(__builtin_amdgcn_fdot2)
#    define FDOT2(a,b,c) __builtin_amdgcn_fdot2((a),(b),(c),false)
#  endif
#endif
#ifndef FDOT2
#  define FDOT2(a,b,c) ((c) + (float)(a).x*(float)(b).x + (float)(a).y*(float)(b).y)
#endif

union h8u { half8_t v; half2_t h[4]; };

// ---------------- K0: pack W matrices to half2 in ws ----------------
__global__ __launch_bounds__(256) void k_prep(
    const float* __restrict__ Wq, const float* __restrict__ Wk, const float* __restrict__ Wv,
    const float* __restrict__ Wg,
    unsigned int* __restrict__ wq2, unsigned int* __restrict__ wk2,
    unsigned int* __restrict__ wv2, unsigned int* __restrict__ wg2)
{
  int t = blockIdx.x * 256 + threadIdx.x;
  if (t < 2048) {
    half2_t a; a.x = (_Float16)Wq[2*t]; a.y = (_Float16)Wq[2*t+1];
    wq2[t] = __builtin_bit_cast(unsigned int, a);
    half2_t b; b.x = (_Float16)Wk[2*t]; b.y = (_Float16)Wk[2*t+1];
    wk2[t] = __builtin_bit_cast(unsigned int, b);
    half2_t c; c.x = (_Float16)Wv[2*t]; c.y = (_Float16)Wv[2*t+1];
    wv2[t] = __builtin_bit_cast(unsigned int, c);
    half2_t d; d.x = (_Float16)Wg[2*t]; d.y = (_Float16)Wg[2*t+1];
    wg2[t] = __builtin_bit_cast(unsigned int, d);
  }
}

// ---------------- K1: MFMA fused QKV + per-(b,n) temporal attention ----------------
// One block = one (b,n). 256 threads = 4 waves; wave w owns i-rows [32w, 32w+32).
// mfma_f32_16x16x32_f16 layouts:
//   A: row m = l&15,  k = 8*(l>>4)+j   (8 f16/lane)
//   B: col n = l&15,  k = 8*(l>>4)+j
//   C/D: col = l&15,  row = 4*(l>>4)+r (4 f32/lane)
#define KSTR 72    // sK row stride (f16)
#define PSTR 136   // sVt / sP row stride (f16)

__device__ __forceinline__ half8_t wfrag(const unsigned int* __restrict__ W2, int e, int k0) {
  // W2 is half2-packed row-major [64][32 dwords]; frag = W[e][k0..k0+7] (16B aligned)
  return *(const half8_t*)(W2 + e * 32 + (k0 >> 1));
}

__global__ __launch_bounds__(256, 2) void k_attn(
    const float* __restrict__ Hi, const float* __restrict__ Hj,
    const unsigned int* __restrict__ wq2, const unsigned int* __restrict__ wk2,
    const unsigned int* __restrict__ wv2,
    const float* __restrict__ bq, const float* __restrict__ bk, const float* __restrict__ bv,
    const float* __restrict__ lgp, const float* __restrict__ ltp,
    float* __restrict__ out)
{
  __shared__ __align__(16) _Float16 sK[TT][KSTR];       // K rows [j][d]      18432 B
  __shared__ __align__(16) _Float16 sVt[DD][PSTR];      // V^T   [e][j]       17408 B
  __shared__ __align__(16) _Float16 sP[4][32][PSTR];    // per-wave Q then P  34816 B
  __shared__ float sDecay[TT];                          //                      512 B

  const int b   = blockIdx.x >> 8;
  const int n   = blockIdx.x & 255;
  const int tid = threadIdx.x;
  const int w   = tid >> 6;
  const int l   = tid & 63;
  const int l16 = l & 15;
  const int lg4 = l >> 4;

  const float gamma = fmaxf(__expf(lgp[0]), 0.01f);
  const float tau   = fmaxf(__expf(ltp[0]), 0.01f);
  const float scale = 1.0f / (8.0f * tau);
  if (tid < TT) {
    float dt = gamma * (float)tid * (1.0f / 127.0f);
    sDecay[tid] = __logf(__expf(-dt) + 1e-8f);
  }

  // ---- A-fragments of Hi/Hj rows ----
  const int row0 = 32 * w;
  half8_t hai[2][2], haj[2][2];
  #pragma unroll
  for (int mt = 0; mt < 2; mt++) {
    const int i = row0 + 16 * mt + l16;
    const float* ri = Hi + (((size_t)b * TT + i) * NN + n) * DD;
    const float* rj = Hj + (((size_t)b * TT + i) * NN + n) * DD;
    #pragma unroll
    for (int ks = 0; ks < 2; ks++) {
      const int k0 = 32 * ks + 8 * lg4;
      float4 a = *(const float4*)(ri + k0);
      float4 c = *(const float4*)(ri + k0 + 4);
      half8_t h;
      h[0]=(_Float16)a.x; h[1]=(_Float16)a.y; h[2]=(_Float16)a.z; h[3]=(_Float16)a.w;
      h[4]=(_Float16)c.x; h[5]=(_Float16)c.y; h[6]=(_Float16)c.z; h[7]=(_Float16)c.w;
      hai[mt][ks] = h;
      a = *(const float4*)(rj + k0);
      c = *(const float4*)(rj + k0 + 4);
      h[0]=(_Float16)a.x; h[1]=(_Float16)a.y; h[2]=(_Float16)a.z; h[3]=(_Float16)a.w;
      h[4]=(_Float16)c.x; h[5]=(_Float16)c.y; h[6]=(_Float16)c.z; h[7]=(_Float16)c.w;
      haj[mt][ks] = h;
    }
  }

  // ---- Q = (Hi @ Wq^T + bq) * scale -> sP[w] rows [i_local][e] (f16) ----
  #pragma unroll
  for (int nt = 0; nt < 4; nt++) {
    const int e = 16 * nt + l16;
    half8_t wb0 = wfrag(wq2, e, 8 * lg4);
    half8_t wb1 = wfrag(wq2, e, 32 + 8 * lg4);
    const float be = bq[e];
    #pragma unroll
    for (int mt = 0; mt < 2; mt++) {
      f32x4 acc = {be, be, be, be};
      acc = __builtin_amdgcn_mfma_f32_16x16x32_f16(hai[mt][0], wb0, acc, 0, 0, 0);
      acc = __builtin_amdgcn_mfma_f32_16x16x32_f16(hai[mt][1], wb1, acc, 0, 0, 0);
      #pragma unroll
      for (int r = 0; r < 4; r++)
        sP[w][16 * mt + 4 * lg4 + r][e] = (_Float16)(acc[r] * scale);
    }
  }

  // ---- K = Hj @ Wk^T + bk -> sK rows [j][d] (f16) ----
  #pragma unroll
  for (int nt = 0; nt < 4; nt++) {
    const int e = 16 * nt + l16;
    half8_t wb0 = wfrag(wk2, e, 8 * lg4);
    half8_t wb1 = wfrag(wk2, e, 32 + 8 * lg4);
    const float be = bk[e];
    #pragma unroll
    for (int mt = 0; mt < 2; mt++) {
      f32x4 acc = {be, be, be, be};
      acc = __builtin_amdgcn_mfma_f32_16x16x32_f16(haj[mt][0], wb0, acc, 0, 0, 0);
      acc = __builtin_amdgcn_mfma_f32_16x16x32_f16(haj[mt][1], wb1, acc, 0, 0, 0);
      #pragma unroll
      for (int r = 0; r < 4; r++)
        sK[row0 + 16 * mt + 4 * lg4 + r][e] = (_Float16)acc[r];
    }
  }

  // ---- V = Hj @ Wv^T + bv -> sVt[e][j] ----
  #pragma unroll
  for (int nt = 0; nt < 4; nt++) {
    const int e = 16 * nt + l16;
    half8_t wb0 = wfrag(wv2, e, 8 * lg4);
    half8_t wb1 = wfrag(wv2, e, 32 + 8 * lg4);
    const float be = bv[e];
    #pragma unroll
    for (int mt = 0; mt < 2; mt++) {
      f32x4 acc = {be, be, be, be};
      acc = __builtin_amdgcn_mfma_f32_16x16x32_f16(haj[mt][0], wb0, acc, 0, 0, 0);
      acc = __builtin_amdgcn_mfma_f32_16x16x32_f16(haj[mt][1], wb1, acc, 0, 0, 0);
      const int jb = row0 + 16 * mt + 4 * lg4;
      half4_t v4;
      v4[0] = (_Float16)acc[0]; v4[1] = (_Float16)acc[1];
      v4[2] = (_Float16)acc[2]; v4[3] = (_Float16)acc[3];
      *(half4_t*)(&sVt[e][jb]) = v4;
    }
  }
  __syncthreads();

  // ---- load Q A-frags from own strip (before overwriting it with P) ----
  half8_t qa[2][2];
  #pragma unroll
  for (int mt = 0; mt < 2; mt++)
    #pragma unroll
    for (int ks = 0; ks < 2; ks++)
      qa[mt][ks] = *(const half8_t*)(&sP[w][16 * mt + l16][32 * ks + 8 * lg4]);

  // ---- S = Q K^T + decay; P = exp(S); rowsum; P -> sP[w] (f16) ----
  float rs[2][4] = {{0.f,0.f,0.f,0.f},{0.f,0.f,0.f,0.f}};
  for (int jt = 0; jt < 8; jt++) {
    const int j = 16 * jt + l16;
    half8_t kb0 = *(const half8_t*)(&sK[j][8 * lg4]);
    half8_t kb1 = *(const half8_t*)(&sK[j][32 + 8 * lg4]);
    #pragma unroll
    for (int mt = 0; mt < 2; mt++) {
      f32x4 acc = {0.f, 0.f, 0.f, 0.f};
      acc = __builtin_amdgcn_mfma_f32_16x16x32_f16(qa[mt][0], kb0, acc, 0, 0, 0);
      acc = __builtin_amdgcn_mfma_f32_16x16x32_f16(qa[mt][1], kb1, acc, 0, 0, 0);
      #pragma unroll
      for (int r = 0; r < 4; r++) {
        const int il = 16 * mt + 4 * lg4 + r;
        int di = (row0 + il) - j; di = di < 0 ? -di : di;
        float p = __expf(acc[r] + sDecay[di]);
        rs[mt][r] += p;
        sP[w][il][j] = (_Float16)p;
      }
    }
  }

  // ---- O = P V ----
  f32x4 oacc[2][4] = {};
  #pragma unroll
  for (int ks = 0; ks < 4; ks++) {
    const int j0 = 32 * ks + 8 * lg4;
    half8_t pa0 = *(const half8_t*)(&sP[w][l16][j0]);
    half8_t pa1 = *(const half8_t*)(&sP[w][16 + l16][j0]);
    #pragma unroll
    for (int nt = 0; nt < 4; nt++) {
      half8_t vb = *(const half8_t*)(&sVt[16 * nt + l16][j0]);
      oacc[0][nt] = __builtin_amdgcn_mfma_f32_16x16x32_f16(pa0, vb, oacc[0][nt], 0, 0, 0);
      oacc[1][nt] = __builtin_amdgcn_mfma_f32_16x16x32_f16(pa1, vb, oacc[1][nt], 0, 0, 0);
    }
  }

  // ---- rowsum reduce; scale + store ----
  #pragma unroll
  for (int mt = 0; mt < 2; mt++)
    #pragma unroll
    for (int r = 0; r < 4; r++) {
      float v = rs[mt][r];
      v += __shfl_xor(v, 1, 64);
      v += __shfl_xor(v, 2, 64);
      v += __shfl_xor(v, 4, 64);
      v += __shfl_xor(v, 8, 64);
      rs[mt][r] = 1.0f / v;
    }
  #pragma unroll
  for (int mt = 0; mt < 2; mt++) {
    #pragma unroll
    for (int r = 0; r < 4; r++) {
      const int i = row0 + 16 * mt + 4 * lg4 + r;
      float* orow = out + (((size_t)b * TT + i) * NN + n) * DD;
      const float rl = rs[mt][r];
      #pragma unroll
      for (int nt = 0; nt < 4; nt++)
        orow[16 * nt + l16] = oacc[mt][nt][r] * rl;
    }
  }
}

// ---------------- K2: adjacency adph[m][n] = softmax_row_m(relu(e1@e2)) in f16 --------
__global__ __launch_bounds__(256) void k_adp(
    const float* __restrict__ e1, const float* __restrict__ e2,
    unsigned short* __restrict__ adph)
{
  const int m = blockIdx.x, n = threadIdx.x;
  float s = 0.f;
  #pragma unroll
  for (int k = 0; k < 32; k++) s += e1[m*32+k] * e2[k*256+n];
  s = fmaxf(s, 0.f);
  __shared__ float red[256];
  red[n] = s; __syncthreads();
  for (int off = 128; off > 0; off >>= 1) {
    if (n < off) red[n] = fmaxf(red[n], red[n+off]);
    __syncthreads();
  }
  float mx = red[0];
  __syncthreads();
  float p = __expf(s - mx);
  red[n] = p; __syncthreads();
  for (int off = 128; off > 0; off >>= 1) {
    if (n < off) red[n] += red[n+off];
    __syncthreads();
  }
  _Float16 h = (_Float16)(p / red[0]);
  adph[m*256 + n] = __builtin_bit_cast(unsigned short, h);
}

// ---------------- K3: MFMA GCN + residual + LN1 (in-place on x) ----------------
// One block = one (b,t) tile. 4 waves; wave w owns m-rows [64w, 64w+64).
// matmul1: G[m][d] = sum_n adp[m][n] * x[n][d]   (A=adph global, B=x^T in LDS)
// matmul2: H[m][e] = relu(sum_d G[m][d] Wg[e][d] + bg[e]); y = x + H; LN over e.
#define GSTR 280   // f16 row stride for sxhT / sgT (560 B, 16B-aligned)

__global__ __launch_bounds__(256, 2) void k_gcn(
    float* __restrict__ x, const unsigned short* __restrict__ adph,
    const unsigned int* __restrict__ wg2, const float* __restrict__ bg,
    const float* __restrict__ g1, const float* __restrict__ b1)
{
  __shared__ __align__(16) _Float16 sxhT[DD][GSTR];  // x^T  [d][n]  35840 B
  __shared__ __align__(16) _Float16 sgT[DD][GSTR];   // G^T  [d][m]  35840 B

  const int tid = threadIdx.x;
  const int w   = tid >> 6;
  const int l   = tid & 63;
  const int l16 = l & 15;
  const int lg4 = l >> 4;
  float* tile = x + (size_t)blockIdx.x * NN * DD;

  // ---- stage x^T into LDS (f16, half2 pairs along n) ----
  {
    const int d2 = tid & 31;   // d-pair index
    const int mg = tid >> 5;   // 0..7
    #pragma unroll
    for (int it = 0; it < 16; it++) {
      const int m0 = mg * 2 + it * 16;   // even; covers all n in pairs
      float2 va = *(const float2*)(tile + (size_t)m0 * DD + 2 * d2);
      float2 vb = *(const float2*)(tile + (size_t)(m0 + 1) * DD + 2 * d2);
      half2_t h0; h0.x = (_Float16)va.x; h0.y = (_Float16)vb.x;
      half2_t h1; h1.x = (_Float16)va.y; h1.y = (_Float16)vb.y;
      *(half2_t*)(&sxhT[2 * d2][m0])     = h0;
      *(half2_t*)(&sxhT[2 * d2 + 1][m0]) = h1;
    }
  }
  __syncthreads();

  // ---- matmul1: acc1[mt][nt] = G tile fragments ----
  f32x4 acc1[4][4] = {};
  for (int ks = 0; ks < 8; ks++) {
    const int k0 = 32 * ks + 8 * lg4;
    half8_t bfr[4], afr[4];
    #pragma unroll
    for (int nt = 0; nt < 4; nt++)
      bfr[nt] = *(const half8_t*)(&sxhT[16 * nt + l16][k0]);
    #pragma unroll
    for (int mt = 0; mt < 4; mt++) {
      const int m = 64 * w + 16 * mt + l16;
      afr[mt] = *(const half8_t*)(adph + m * 256 + k0);
    }
    #pragma unroll
    for (int mt = 0; mt < 4; mt++)
      #pragma unroll
      for (int nt = 0; nt < 4; nt++)
        acc1[mt][nt] = __builtin_amdgcn_mfma_f32_16x16x32_f16(afr[mt], bfr[nt], acc1[mt][nt], 0, 0, 0);
  }

  // ---- write G^T to LDS (b64, 4 consecutive m per lane) ----
  #pragma unroll
  for (int mt = 0; mt < 4; mt++)
    #pragma unroll
    for (int nt = 0; nt < 4; nt++) {
      half4_t g4;
      g4[0] = (_Float16)acc1[mt][nt][0]; g4[1] = (_Float16)acc1[mt][nt][1];
      g4[2] = (_Float16)acc1[mt][nt][2]; g4[3] = (_Float16)acc1[mt][nt][3];
      *(half4_t*)(&sgT[16 * nt + l16][64 * w + 16 * mt + 4 * lg4]) = g4;
    }
  __syncthreads();

  // ---- matmul2 + fused relu/residual/LN epilogue, per mt ----
  half8_t wb[4][2];
  float bgv[4], g1v[4], b1v[4];
  #pragma unroll
  for (int et = 0; et < 4; et++) {
    const int e = 16 * et + l16;
    wb[et][0] = wfrag(wg2, e, 8 * lg4);
    wb[et][1] = wfrag(wg2, e, 32 + 8 * lg4);
    bgv[et] = bg[e]; g1v[et] = g1[e]; b1v[et] = b1[e];
  }

  #pragma unroll 1
  for (int mt = 0; mt < 4; mt++) {
    // A-frags of G from sgT (scalar gather, broadcast-friendly)
    half8_t ga[2];
    #pragma unroll
    for (int ks = 0; ks < 2; ks++) {
      half8_t h;
      #pragma unroll
      for (int j = 0; j < 8; j++)
        h[j] = sgT[32 * ks + 8 * lg4 + j][64 * w + 16 * mt + l16];
      ga[ks] = h;
    }
    f32x4 acc2[4];
    #pragma unroll
    for (int et = 0; et < 4; et++) {
      f32x4 a = {bgv[et], bgv[et], bgv[et], bgv[et]};
      a = __builtin_amdgcn_mfma_f32_16x16x32_f16(ga[0], wb[et][0], a, 0, 0, 0);
      a = __builtin_amdgcn_mfma_f32_16x16x32_f16(ga[1], wb[et][1], a, 0, 0, 0);
      acc2[et] = a;
    }
    // epilogue: rows mrow = 64w+16mt+4lg4+r
    #pragma unroll
    for (int r = 0; r < 4; r++) {
      const int mrow = 64 * w + 16 * mt + 4 * lg4 + r;
      float* xr = tile + (size_t)mrow * DD;
      float y[4], s1 = 0.f, s2 = 0.f;
      #pragma unroll
      for (int et = 0; et < 4; et++) {
        float h = fmaxf(acc2[et][r], 0.f);
        float yv = xr[16 * et + l16] + h;
        y[et] = yv; s1 += yv; s2 += yv * yv;
      }
      #pragma unroll
      for (int off = 1; off < 16; off <<= 1) {
        s1 += __shfl_xor(s1, off, 64);
        s2 += __shfl_xor(s2, off, 64);
      }
      const float mean = s1 * (1.f / 64.f);
      const float var  = fmaxf(s2 * (1.f / 64.f) - mean * mean, 0.f);
      const float rstd = rsqrtf(var + 1e-5f);
      #pragma unroll
      for (int et = 0; et < 4; et++)
        xr[16 * et + l16] = (y[et] - mean) * rstd * g1v[et] + b1v[et];
    }
  }
}

// ---------------- K3b: GI[t][seq][192] = x_ln1 @ Wih^T + bih  (fp16, parallel) ----------
__global__ __launch_bounds__(256) void k_gih(
    const float* __restrict__ x, const float* __restrict__ Wih,
    const float* __restrict__ bih, unsigned int* __restrict__ GI2)
{
  __shared__ unsigned int sW[192*32];   // 24KB packed half2 weights
  __shared__ unsigned int sbuf[256*33]; // overlay: x-stage [256][33], then out-stage [256][25]
  const int tid = threadIdx.x;
  const int b = blockIdx.x >> 7, t = blockIdx.x & 127;
  const float* xt = x + (((size_t)b * TT + t) * NN) * DD;

  for (int idx = tid; idx < 192*32; idx += 256) {
    float2 w = ((const float2*)Wih)[idx];
    half2_t h; h.x = (_Float16)w.x; h.y = (_Float16)w.y;
    sW[idx] = __builtin_bit_cast(unsigned int, h);
  }
  for (int idx = tid; idx < 256*32; idx += 256) {
    int n = idx >> 5, k = idx & 31;
    float2 v = ((const float2*)xt)[idx];
    half2_t h; h.x = (_Float16)v.x; h.y = (_Float16)v.y;
    sbuf[n*33 + k] = __builtin_bit_cast(unsigned int, h);
  }
  __syncthreads();
  half2_t xr[32];
  #pragma unroll
  for (int k = 0; k < 32; k++) xr[k] = __builtin_bit_cast(half2_t, sbuf[tid*33 + k]);
  __syncthreads();

  const size_t blockbase = ((size_t)t * 2048 + b * 256) * 96;  // dword index
  for (int c = 0; c < 4; c++) {
    #pragma unroll 2
    for (int j2 = 0; j2 < 24; j2++) {
      int e0 = c*48 + 2*j2;
      float a0 = bih[e0], a1 = bih[e0+1];
      const half8_t* w0 = (const half8_t*)(sW + e0*32);
      const half8_t* w1 = (const half8_t*)(sW + (e0+1)*32);
      #pragma unroll
      for (int kq = 0; kq < 8; kq++) {
        h8u ua, ub; ua.v = w0[kq]; ub.v = w1[kq];
        #pragma unroll
        for (int m = 0; m < 4; m++) {
          a0 = FDOT2(ua.h[m], xr[4*kq+m], a0);
          a1 = FDOT2(ub.h[m], xr[4*kq+m], a1);
        }
      }
      half2_t o; o.x = (_Float16)a0; o.y = (_Float16)a1;
      sbuf[tid*25 + j2] = __builtin_bit_cast(unsigned int, o);
    }
    __syncthreads();
    for (int idx = tid; idx < 6144; idx += 256) {
      int n = idx / 24, e2 = idx % 24;
      GI2[blockbase + (size_t)n*96 + c*24 + e2] = sbuf[n*25 + e2];
    }
    __syncthreads();
  }
}

// ---------------- K4: GRU over T (gi precomputed) + LN2 + residual ----------------
__global__ __launch_bounds__(256) void k_gru_gi(
    float* __restrict__ x, const _Float16* __restrict__ GIh,
    const float* __restrict__ Whh, const float* __restrict__ bhh,
    const float* __restrict__ g2, const float* __restrict__ b2)
{
  __shared__ __align__(16) _Float16 hsh[4*64];
  __shared__ float ghs[4*192];
  const int tid = threadIdx.x;
  const int b = blockIdx.x >> 6, n4 = blockIdx.x & 63;
  const int s = tid >> 6, d = tid & 63;

  half2_t wh[32];
  float bh = 0.f;
  if (tid < 192) {
    bh = bhh[tid];
    const float2* wr = (const float2*)Whh;
    #pragma unroll
    for (int k = 0; k < 32; k++) {
      float2 w = wr[tid*32 + k];
      half2_t h; h.x = (_Float16)w.x; h.y = (_Float16)w.y;
      wh[k] = h;
    }
  }
  hsh[tid] = (_Float16)0.f;
  const float lng = g2[d], lnb = b2[d];
  float hreg = 0.f;
  size_t gioff = ((size_t)b*256 + n4*4 + s)*192 + d;
  size_t xoff  = (((size_t)b * TT) * NN + n4*4 + s)*DD + d;
  __syncthreads();

  for (int t = 0; t < TT; t++) {
    float gir = (float)GIh[gioff];
    float giz = (float)GIh[gioff + 64];
    float gin = (float)GIh[gioff + 128];
    float xv  = x[xoff];

    if (tid < 192) {
      float a0 = bh, a1 = bh, a2 = bh, a3 = bh;
      const half8_t* h8 = (const half8_t*)hsh;
      #pragma unroll
      for (int kq = 0; kq < 8; kq++) {
        h8u u0, u1, u2, u3;
        u0.v = h8[kq]; u1.v = h8[8+kq]; u2.v = h8[16+kq]; u3.v = h8[24+kq];
        #pragma unroll
        for (int m = 0; m < 4; m++) {
          half2_t w = wh[4*kq + m];
          a0 = FDOT2(w, u0.h[m], a0);
          a1 = FDOT2(w, u1.h[m], a1);
          a2 = FDOT2(w, u2.h[m], a2);
          a3 = FDOT2(w, u3.h[m], a3);
        }
      }
      ghs[tid] = a0; ghs[192 + tid] = a1; ghs[384 + tid] = a2; ghs[576 + tid] = a3;
    }
    __syncthreads();

    float rr = gir + ghs[s*192 + d];
    float zz = giz + ghs[s*192 + 64 + d];
    float hn_ = ghs[s*192 + 128 + d];
    float r = 1.f / (1.f + __expf(-rr));
    float z = 1.f / (1.f + __expf(-zz));
    float e = __expf(2.f * (gin + r * hn_));
    float nt = 1.f - 2.f / (e + 1.f);     // tanh, overflow-safe
    float hn = (1.f - z) * nt + z * hreg;
    hreg = hn;

    float yv = xv + hn;
    float s1 = yv, s2v = yv * yv;
    #pragma unroll
    for (int off = 32; off > 0; off >>= 1) {
      s1  += __shfl_xor(s1,  off, 64);
      s2v += __shfl_xor(s2v, off, 64);
    }
    float mean = s1 * 0.015625f;
    float var  = fmaxf(s2v * 0.015625f - mean * mean, 0.f);
    float hm = (yv - mean) * rsqrtf(var + 1e-5f) * lng + lnb;

    x[xoff] = xv + hm;
    hsh[tid] = (_Float16)hn;
    __syncthreads();

    gioff += (size_t)2048 * 192;
    xoff  += (size_t)NN * DD;
  }
}

// ---------------- K4 fallback: original fused GRU (ws too small for GI) ----------------
__global__ __launch_bounds__(256) void k_gru(
    float* __restrict__ x,
    const float* __restrict__ Wih, const float* __restrict__ Whh,
    const float* __restrict__ bih, const float* __restrict__ bhh,
    const float* __restrict__ g2, const float* __restrict__ b2)
{
  __shared__ half2_t sWi[192][33];
  __shared__ half2_t sWh[192][33];
  __shared__ float   xs[4][64];
  __shared__ half2_t xs_h[4][32];
  __shared__ float   hs_f[4][64];
  __shared__ half2_t hs_h[4][32];
  __shared__ float   gis[4][192];
  __shared__ float   ghs[4][192];

  const int b  = blockIdx.x >> 6;
  const int ng = blockIdx.x & 63;

  for (int idx = threadIdx.x; idx < 192 * 32; idx += 256) {
    int g = idx >> 5, dh = idx & 31;
    half2_t hv; hv.x = (_Float16)Wih[g*64 + 2*dh]; hv.y = (_Float16)Wih[g*64 + 2*dh + 1];
    sWi[g][dh] = hv;
    half2_t hw; hw.x = (_Float16)Whh[g*64 + 2*dh]; hw.y = (_Float16)Whh[g*64 + 2*dh + 1];
    sWh[g][dh] = hw;
  }
  const int s_d = threadIdx.x >> 6;
  const int d_d = threadIdx.x & 63;
  hs_f[s_d][d_d] = 0.f;
  ((_Float16*)hs_h[s_d])[d_d] = (_Float16)0.f;
  const float lng = g2[d_d], lnb = b2[d_d];

  int   tsk_s[3], tsk_g[3];
  float tb_i[3], tb_h[3];
  #pragma unroll
  for (int k = 0; k < 3; k++) {
    int task = threadIdx.x + k * 256;
    tsk_s[k] = task / 192; tsk_g[k] = task % 192;
    tb_i[k] = bih[tsk_g[k]]; tb_h[k] = bhh[tsk_g[k]];
  }
  __syncthreads();

  const size_t base = (((size_t)b * TT) * NN + ng * 4) * DD;
  for (int t = 0; t < TT; t++) {
    const size_t row = base + (size_t)t * NN * DD + s_d * 64 + d_d;
    float xv = x[row];
    xs[s_d][d_d] = xv;
    ((_Float16*)xs_h[s_d])[d_d] = (_Float16)xv;
    __syncthreads();

    #pragma unroll
    for (int k = 0; k < 3; k++) {
      int s = tsk_s[k], g = tsk_g[k];
      float ai = tb_i[k], ah = tb_h[k];
      #pragma unroll
      for (int dh = 0; dh < 32; dh++) {
        ai = FDOT2(sWi[g][dh], xs_h[s][dh], ai);
        ah = FDOT2(sWh[g][dh], hs_h[s][dh], ah);
      }
      gis[s][g] = ai; ghs[s][g] = ah;
    }
    __syncthreads();

    float gr = gis[s_d][d_d]      + ghs[s_d][d_d];
    float gz = gis[s_d][64 + d_d] + ghs[s_d][64 + d_d];
    float r  = 1.f / (1.f + __expf(-gr));
    float z  = 1.f / (1.f + __expf(-gz));
    float nn = tanhf(gis[s_d][128 + d_d] + r * ghs[s_d][128 + d_d]);
    float ho = hs_f[s_d][d_d];
    float hn = (1.f - z) * nn + z * ho;

    float yv = xs[s_d][d_d] + hn;
    float s1 = yv, s2 = yv * yv;
    #pragma unroll
    for (int off = 32; off > 0; off >>= 1) {
      s1 += __shfl_xor(s1, off, 64);
      s2 += __shfl_xor(s2, off, 64);
    }
    float mean = s1 * (1.f / 64.f);
    float var  = fmaxf(s2 * (1.f / 64.f) - mean * mean, 0.f);
    float hm = (yv - mean) * rsqrtf(var + 1e-5f) * lng + lnb;

    x[row] = xs[s_d][d_d] + hm;
    hs_f[s_d][d_d] = hn;
    ((_Float16*)hs_h[s_d])[d_d] = (_Float16)hn;
    __syncthreads();
  }
}

extern "C" void kernel_launch(void* const* d_in, const int* in_sizes, int n_in,
                              void* d_out, int out_size, void* d_ws, size_t ws_size,
                              hipStream_t stream) {
  const float* Hi  = (const float*)d_in[0];
  const float* Hj  = (const float*)d_in[1];
  const float* Wq  = (const float*)d_in[2];  const float* bq = (const float*)d_in[3];
  const float* Wk  = (const float*)d_in[4];  const float* bk = (const float*)d_in[5];
  const float* Wv  = (const float*)d_in[6];  const float* bv = (const float*)d_in[7];
  const float* lg  = (const float*)d_in[8];  const float* lt = (const float*)d_in[9];
  const float* e1  = (const float*)d_in[10]; const float* e2 = (const float*)d_in[11];
  const float* Wg  = (const float*)d_in[12]; const float* bg = (const float*)d_in[13];
  const float* g1  = (const float*)d_in[14]; const float* b1 = (const float*)d_in[15];
  const float* Wih = (const float*)d_in[16]; const float* Whh = (const float*)d_in[17];
  const float* bih = (const float*)d_in[18]; const float* bhh = (const float*)d_in[19];
  const float* g2  = (const float*)d_in[20]; const float* b2  = (const float*)d_in[21];
  float* out  = (float*)d_out;

  unsigned short* adph = (unsigned short*)d_ws;        // 128KB @ offset 0 (f16 adjacency)
  unsigned int* wg2 = (unsigned int*)d_ws + 32768;     // 8KB @ offset 128KB
  unsigned int* wq2 = (unsigned int*)d_ws + 65536;     // 3 x 8KB @ offset 256KB
  unsigned int* wk2 = wq2 + 2048;
  unsigned int* wv2 = wk2 + 2048;
  const size_t gi_off = 286720;                        // byte offset, 512-aligned
  const size_t gi_bytes = (size_t)2048 * TT * 192 * 2; // 96MB fp16
  const bool use_gi = ws_size >= gi_off + gi_bytes;
  unsigned int* GI2 = (unsigned int*)((char*)d_ws + gi_off);
  _Float16*     GIh = (_Float16*)((char*)d_ws + gi_off);

  k_prep<<<dim3(8),     dim3(256), 0, stream>>>(Wq, Wk, Wv, Wg, wq2, wk2, wv2, wg2);
  k_attn<<<dim3(BB*NN), dim3(256), 0, stream>>>(Hi, Hj, wq2, wk2, wv2, bq, bk, bv, lg, lt, out);
  k_adp <<<dim3(NN),    dim3(256), 0, stream>>>(e1, e2, adph);
  k_gcn <<<dim3(BB*TT), dim3(256), 0, stream>>>(out, adph, wg2, bg, g1, b1);
  if (use_gi) {
    k_gih   <<<dim3(BB*TT), dim3(256), 0, stream>>>(out, Wih, bih, GI2);
    k_gru_gi<<<dim3(512),   dim3(256), 0, stream>>>(out, GIh, Whh, bhh, g2, b2);
  } else {
    k_gru   <<<dim3(512),   dim3(256), 0, stream>>>(out, Wih, Whh, bih, bhh, g2, b2);
  }
}

// Round 5
// 549.984 us; speedup vs baseline: 1.8896x; 1.0166x over previous
//
#include <hip/hip_runtime.h>
#include <cstddef>

#define BB 8
#define TT 128
#define NN 256
#define DD 64

typedef _Float16 half2_t __attribute__((ext_vector_type(2)));
typedef _Float16 half4_t __attribute__((ext_vector_type(4)));
typedef _Float16 half8_t __attribute__((ext_vector_type(8)));
typedef float f32x4 __attribute__((ext_vector_type(4)));

#if defined(__has_builtin)
#  if __has_builtin(__builtin_amdgcn_fdot2)
#    define FDOT2(a,b,c) __builtin_amdgcn_fdot2((a),(b),(c),false)
#  endif
#endif
#ifndef FDOT2
#  define FDOT2(a,b,c) ((c) + (float)(a).x*(float)(b).x + (float)(a).y*(float)(b).y)
#endif

union h8u { half8_t v; half2_t h[4]; };

// ---------------- K0: pack W matrices to half2 in ws ----------------
__global__ __launch_bounds__(256) void k_prep(
    const float* __restrict__ Wq, const float* __restrict__ Wk, const float* __restrict__ Wv,
    const float* __restrict__ Wg,
    unsigned int* __restrict__ wq2, unsigned int* __restrict__ wk2,
    unsigned int* __restrict__ wv2, unsigned int* __restrict__ wg2)
{
  int t = blockIdx.x * 256 + threadIdx.x;
  if (t < 2048) {
    half2_t a; a.x = (_Float16)Wq[2*t]; a.y = (_Float16)Wq[2*t+1];
    wq2[t] = __builtin_bit_cast(unsigned int, a);
    half2_t b; b.x = (_Float16)Wk[2*t]; b.y = (_Float16)Wk[2*t+1];
    wk2[t] = __builtin_bit_cast(unsigned int, b);
    half2_t c; c.x = (_Float16)Wv[2*t]; c.y = (_Float16)Wv[2*t+1];
    wv2[t] = __builtin_bit_cast(unsigned int, c);
    half2_t d; d.x = (_Float16)Wg[2*t]; d.y = (_Float16)Wg[2*t+1];
    wg2[t] = __builtin_bit_cast(unsigned int, d);
  }
}

// ---------------- K1: MFMA fused QKV + per-(b,n) temporal attention ----------------
// One block = one (b,n). 256 threads = 4 waves; wave w owns i-rows [32w, 32w+32).
// mfma_f32_16x16x32_f16 layouts:
//   A: row m = l&15,  k = 8*(l>>4)+j   (8 f16/lane)
//   B: col n = l&15,  k = 8*(l>>4)+j
//   C/D: col = l&15,  row = 4*(l>>4)+r (4 f32/lane)
#define KSTR 72    // sK row stride (f16)
#define PSTR 136   // sVt / sP row stride (f16)

__device__ __forceinline__ half8_t wfrag(const unsigned int* __restrict__ W2, int e, int k0) {
  // W2 is half2-packed row-major [64][32 dwords]; frag = W[e][k0..k0+7] (16B aligned)
  return *(const half8_t*)(W2 + e * 32 + (k0 >> 1));
}

__global__ __launch_bounds__(256, 2) void k_attn(
    const float* __restrict__ Hi, const float* __restrict__ Hj,
    const unsigned int* __restrict__ wq2, const unsigned int* __restrict__ wk2,
    const unsigned int* __restrict__ wv2,
    const float* __restrict__ bq, const float* __restrict__ bk, const float* __restrict__ bv,
    const float* __restrict__ lgp, const float* __restrict__ ltp,
    float* __restrict__ out)
{
  __shared__ __align__(16) _Float16 sK[TT][KSTR];       // K rows [j][d]      18432 B
  __shared__ __align__(16) _Float16 sVt[DD][PSTR];      // V^T   [e][j]       17408 B
  __shared__ __align__(16) _Float16 sP[4][32][PSTR];    // per-wave Q then P  34816 B
  __shared__ float sDecay[TT];                          //                      512 B

  const int b   = blockIdx.x >> 8;
  const int n   = blockIdx.x & 255;
  const int tid = threadIdx.x;
  const int w   = tid >> 6;
  const int l   = tid & 63;
  const int l16 = l & 15;
  const int lg4 = l >> 4;

  const float gamma = fmaxf(__expf(lgp[0]), 0.01f);
  const float tau   = fmaxf(__expf(ltp[0]), 0.01f);
  const float scale = 1.0f / (8.0f * tau);
  if (tid < TT) {
    float dt = gamma * (float)tid * (1.0f / 127.0f);
    sDecay[tid] = __logf(__expf(-dt) + 1e-8f);
  }

  // ---- A-fragments of Hi/Hj rows ----
  const int row0 = 32 * w;
  half8_t hai[2][2], haj[2][2];
  #pragma unroll
  for (int mt = 0; mt < 2; mt++) {
    const int i = row0 + 16 * mt + l16;
    const float* ri = Hi + (((size_t)b * TT + i) * NN + n) * DD;
    const float* rj = Hj + (((size_t)b * TT + i) * NN + n) * DD;
    #pragma unroll
    for (int ks = 0; ks < 2; ks++) {
      const int k0 = 32 * ks + 8 * lg4;
      float4 a = *(const float4*)(ri + k0);
      float4 c = *(const float4*)(ri + k0 + 4);
      half8_t h;
      h[0]=(_Float16)a.x; h[1]=(_Float16)a.y; h[2]=(_Float16)a.z; h[3]=(_Float16)a.w;
      h[4]=(_Float16)c.x; h[5]=(_Float16)c.y; h[6]=(_Float16)c.z; h[7]=(_Float16)c.w;
      hai[mt][ks] = h;
      a = *(const float4*)(rj + k0);
      c = *(const float4*)(rj + k0 + 4);
      h[0]=(_Float16)a.x; h[1]=(_Float16)a.y; h[2]=(_Float16)a.z; h[3]=(_Float16)a.w;
      h[4]=(_Float16)c.x; h[5]=(_Float16)c.y; h[6]=(_Float16)c.z; h[7]=(_Float16)c.w;
      haj[mt][ks] = h;
    }
  }

  // ---- Q = (Hi @ Wq^T + bq) * scale -> sP[w] rows [i_local][e] (f16) ----
  #pragma unroll
  for (int nt = 0; nt < 4; nt++) {
    const int e = 16 * nt + l16;
    half8_t wb0 = wfrag(wq2, e, 8 * lg4);
    half8_t wb1 = wfrag(wq2, e, 32 + 8 * lg4);
    const float be = bq[e];
    #pragma unroll
    for (int mt = 0; mt < 2; mt++) {
      f32x4 acc = {be, be, be, be};
      acc = __builtin_amdgcn_mfma_f32_16x16x32_f16(hai[mt][0], wb0, acc, 0, 0, 0);
      acc = __builtin_amdgcn_mfma_f32_16x16x32_f16(hai[mt][1], wb1, acc, 0, 0, 0);
      #pragma unroll
      for (int r = 0; r < 4; r++)
        sP[w][16 * mt + 4 * lg4 + r][e] = (_Float16)(acc[r] * scale);
    }
  }

  // ---- K = Hj @ Wk^T + bk -> sK rows [j][d] (f16) ----
  #pragma unroll
  for (int nt = 0; nt < 4; nt++) {
    const int e = 16 * nt + l16;
    half8_t wb0 = wfrag(wk2, e, 8 * lg4);
    half8_t wb1 = wfrag(wk2, e, 32 + 8 * lg4);
    const float be = bk[e];
    #pragma unroll
    for (int mt = 0; mt < 2; mt++) {
      f32x4 acc = {be, be, be, be};
      acc = __builtin_amdgcn_mfma_f32_16x16x32_f16(haj[mt][0], wb0, acc, 0, 0, 0);
      acc = __builtin_amdgcn_mfma_f32_16x16x32_f16(haj[mt][1], wb1, acc, 0, 0, 0);
      #pragma unroll
      for (int r = 0; r < 4; r++)
        sK[row0 + 16 * mt + 4 * lg4 + r][e] = (_Float16)acc[r];
    }
  }

  // ---- V = Hj @ Wv^T + bv -> sVt[e][j] ----
  #pragma unroll
  for (int nt = 0; nt < 4; nt++) {
    const int e = 16 * nt + l16;
    half8_t wb0 = wfrag(wv2, e, 8 * lg4);
    half8_t wb1 = wfrag(wv2, e, 32 + 8 * lg4);
    const float be = bv[e];
    #pragma unroll
    for (int mt = 0; mt < 2; mt++) {
      f32x4 acc = {be, be, be, be};
      acc = __builtin_amdgcn_mfma_f32_16x16x32_f16(haj[mt][0], wb0, acc, 0, 0, 0);
      acc = __builtin_amdgcn_mfma_f32_16x16x32_f16(haj[mt][1], wb1, acc, 0, 0, 0);
      const int jb = row0 + 16 * mt + 4 * lg4;
      half4_t v4;
      v4[0] = (_Float16)acc[0]; v4[1] = (_Float16)acc[1];
      v4[2] = (_Float16)acc[2]; v4[3] = (_Float16)acc[3];
      *(half4_t*)(&sVt[e][jb]) = v4;
    }
  }
  __syncthreads();

  // ---- load Q A-frags from own strip (before overwriting it with P) ----
  half8_t qa[2][2];
  #pragma unroll
  for (int mt = 0; mt < 2; mt++)
    #pragma unroll
    for (int ks = 0; ks < 2; ks++)
      qa[mt][ks] = *(const half8_t*)(&sP[w][16 * mt + l16][32 * ks + 8 * lg4]);

  // ---- S = Q K^T + decay; P = exp(S); rowsum; P -> sP[w] (f16) ----
  float rs[2][4] = {{0.f,0.f,0.f,0.f},{0.f,0.f,0.f,0.f}};
  for (int jt = 0; jt < 8; jt++) {
    const int j = 16 * jt + l16;
    half8_t kb0 = *(const half8_t*)(&sK[j][8 * lg4]);
    half8_t kb1 = *(const half8_t*)(&sK[j][32 + 8 * lg4]);
    #pragma unroll
    for (int mt = 0; mt < 2; mt++) {
      f32x4 acc = {0.f, 0.f, 0.f, 0.f};
      acc = __builtin_amdgcn_mfma_f32_16x16x32_f16(qa[mt][0], kb0, acc, 0, 0, 0);
      acc = __builtin_amdgcn_mfma_f32_16x16x32_f16(qa[mt][1], kb1, acc, 0, 0, 0);
      #pragma unroll
      for (int r = 0; r < 4; r++) {
        const int il = 16 * mt + 4 * lg4 + r;
        int di = (row0 + il) - j; di = di < 0 ? -di : di;
        float p = __expf(acc[r] + sDecay[di]);
        rs[mt][r] += p;
        sP[w][il][j] = (_Float16)p;
      }
    }
  }

  // ---- O = P V ----
  f32x4 oacc[2][4] = {};
  #pragma unroll
  for (int ks = 0; ks < 4; ks++) {
    const int j0 = 32 * ks + 8 * lg4;
    half8_t pa0 = *(const half8_t*)(&sP[w][l16][j0]);
    half8_t pa1 = *(const half8_t*)(&sP[w][16 + l16][j0]);
    #pragma unroll
    for (int nt = 0; nt < 4; nt++) {
      half8_t vb = *(const half8_t*)(&sVt[16 * nt + l16][j0]);
      oacc[0][nt] = __builtin_amdgcn_mfma_f32_16x16x32_f16(pa0, vb, oacc[0][nt], 0, 0, 0);
      oacc[1][nt] = __builtin_amdgcn_mfma_f32_16x16x32_f16(pa1, vb, oacc[1][nt], 0, 0, 0);
    }
  }

  // ---- rowsum reduce; scale + store ----
  #pragma unroll
  for (int mt = 0; mt < 2; mt++)
    #pragma unroll
    for (int r = 0; r < 4; r++) {
      float v = rs[mt][r];
      v += __shfl_xor(v, 1, 64);
      v += __shfl_xor(v, 2, 64);
      v += __shfl_xor(v, 4, 64);
      v += __shfl_xor(v, 8, 64);
      rs[mt][r] = 1.0f / v;
    }
  #pragma unroll
  for (int mt = 0; mt < 2; mt++) {
    #pragma unroll
    for (int r = 0; r < 4; r++) {
      const int i = row0 + 16 * mt + 4 * lg4 + r;
      float* orow = out + (((size_t)b * TT + i) * NN + n) * DD;
      const float rl = rs[mt][r];
      #pragma unroll
      for (int nt = 0; nt < 4; nt++)
        orow[16 * nt + l16] = oacc[mt][nt][r] * rl;
    }
  }
}

// ---------------- K2: adjacency adph[m][n] = softmax_row_m(relu(e1@e2)) in f16 --------
__global__ __launch_bounds__(256) void k_adp(
    const float* __restrict__ e1, const float* __restrict__ e2,
    unsigned short* __restrict__ adph)
{
  const int m = blockIdx.x, n = threadIdx.x;
  float s = 0.f;
  #pragma unroll
  for (int k = 0; k < 32; k++) s += e1[m*32+k] * e2[k*256+n];
  s = fmaxf(s, 0.f);
  __shared__ float red[256];
  red[n] = s; __syncthreads();
  for (int off = 128; off > 0; off >>= 1) {
    if (n < off) red[n] = fmaxf(red[n], red[n+off]);
    __syncthreads();
  }
  float mx = red[0];
  __syncthreads();
  float p = __expf(s - mx);
  red[n] = p; __syncthreads();
  for (int off = 128; off > 0; off >>= 1) {
    if (n < off) red[n] += red[n+off];
    __syncthreads();
  }
  _Float16 h = (_Float16)(p / red[0]);
  adph[m*256 + n] = __builtin_bit_cast(unsigned short, h);
}

// ---------------- K3: MFMA GCN + residual + LN1 (in-place on x) ----------------
// One block = one (b,t) tile. 4 waves; wave w owns m-rows [64w, 64w+64).
// matmul1: G[m][d] = sum_n adp[m][n] * x[n][d]   (A=adph global, B=x^T in LDS)
// matmul2: H[m][e] = relu(sum_d G[m][d] Wg[e][d] + bg[e]); y = x + H; LN over e.
#define GSTR 280   // f16 row stride for sxhT / sgT (560 B, 16B-aligned)

__global__ __launch_bounds__(256, 2) void k_gcn(
    float* __restrict__ x, const unsigned short* __restrict__ adph,
    const unsigned int* __restrict__ wg2, const float* __restrict__ bg,
    const float* __restrict__ g1, const float* __restrict__ b1)
{
  __shared__ __align__(16) _Float16 sxhT[DD][GSTR];  // x^T  [d][n]  35840 B
  __shared__ __align__(16) _Float16 sgT[DD][GSTR];   // G^T  [d][m]  35840 B

  const int tid = threadIdx.x;
  const int w   = tid >> 6;
  const int l   = tid & 63;
  const int l16 = l & 15;
  const int lg4 = l >> 4;
  float* tile = x + (size_t)blockIdx.x * NN * DD;

  // ---- stage x^T into LDS (f16, half2 pairs along n) ----
  {
    const int d2 = tid & 31;   // d-pair index
    const int mg = tid >> 5;   // 0..7
    #pragma unroll
    for (int it = 0; it < 16; it++) {
      const int m0 = mg * 2 + it * 16;   // even; covers all n in pairs
      float2 va = *(const float2*)(tile + (size_t)m0 * DD + 2 * d2);
      float2 vb = *(const float2*)(tile + (size_t)(m0 + 1) * DD + 2 * d2);
      half2_t h0; h0.x = (_Float16)va.x; h0.y = (_Float16)vb.x;
      half2_t h1; h1.x = (_Float16)va.y; h1.y = (_Float16)vb.y;
      *(half2_t*)(&sxhT[2 * d2][m0])     = h0;
      *(half2_t*)(&sxhT[2 * d2 + 1][m0]) = h1;
    }
  }
  __syncthreads();

  // ---- matmul1: acc1[mt][nt] = G tile fragments ----
  f32x4 acc1[4][4] = {};
  for (int ks = 0; ks < 8; ks++) {
    const int k0 = 32 * ks + 8 * lg4;
    half8_t bfr[4], afr[4];
    #pragma unroll
    for (int nt = 0; nt < 4; nt++)
      bfr[nt] = *(const half8_t*)(&sxhT[16 * nt + l16][k0]);
    #pragma unroll
    for (int mt = 0; mt < 4; mt++) {
      const int m = 64 * w + 16 * mt + l16;
      afr[mt] = *(const half8_t*)(adph + m * 256 + k0);
    }
    #pragma unroll
    for (int mt = 0; mt < 4; mt++)
      #pragma unroll
      for (int nt = 0; nt < 4; nt++)
        acc1[mt][nt] = __builtin_amdgcn_mfma_f32_16x16x32_f16(afr[mt], bfr[nt], acc1[mt][nt], 0, 0, 0);
  }

  // ---- write G^T to LDS (b64, 4 consecutive m per lane) ----
  #pragma unroll
  for (int mt = 0; mt < 4; mt++)
    #pragma unroll
    for (int nt = 0; nt < 4; nt++) {
      half4_t g4;
      g4[0] = (_Float16)acc1[mt][nt][0]; g4[1] = (_Float16)acc1[mt][nt][1];
      g4[2] = (_Float16)acc1[mt][nt][2]; g4[3] = (_Float16)acc1[mt][nt][3];
      *(half4_t*)(&sgT[16 * nt + l16][64 * w + 16 * mt + 4 * lg4]) = g4;
    }
  __syncthreads();

  // ---- matmul2 + fused relu/residual/LN epilogue, per mt ----
  half8_t wb[4][2];
  float bgv[4], g1v[4], b1v[4];
  #pragma unroll
  for (int et = 0; et < 4; et++) {
    const int e = 16 * et + l16;
    wb[et][0] = wfrag(wg2, e, 8 * lg4);
    wb[et][1] = wfrag(wg2, e, 32 + 8 * lg4);
    bgv[et] = bg[e]; g1v[et] = g1[e]; b1v[et] = b1[e];
  }

  #pragma unroll 1
  for (int mt = 0; mt < 4; mt++) {
    // A-frags of G from sgT (scalar gather, broadcast-friendly)
    half8_t ga[2];
    #pragma unroll
    for (int ks = 0; ks < 2; ks++) {
      half8_t h;
      #pragma unroll
      for (int j = 0; j < 8; j++)
        h[j] = sgT[32 * ks + 8 * lg4 + j][64 * w + 16 * mt + l16];
      ga[ks] = h;
    }
    f32x4 acc2[4];
    #pragma unroll
    for (int et = 0; et < 4; et++) {
      f32x4 a = {bgv[et], bgv[et], bgv[et], bgv[et]};
      a = __builtin_amdgcn_mfma_f32_16x16x32_f16(ga[0], wb[et][0], a, 0, 0, 0);
      a = __builtin_amdgcn_mfma_f32_16x16x32_f16(ga[1], wb[et][1], a, 0, 0, 0);
      acc2[et] = a;
    }
    // epilogue: rows mrow = 64w+16mt+4lg4+r
    #pragma unroll
    for (int r = 0; r < 4; r++) {
      const int mrow = 64 * w + 16 * mt + 4 * lg4 + r;
      float* xr = tile + (size_t)mrow * DD;
      float y[4], s1 = 0.f, s2 = 0.f;
      #pragma unroll
      for (int et = 0; et < 4; et++) {
        float h = fmaxf(acc2[et][r], 0.f);
        float yv = xr[16 * et + l16] + h;
        y[et] = yv; s1 += yv; s2 += yv * yv;
      }
      #pragma unroll
      for (int off = 1; off < 16; off <<= 1) {
        s1 += __shfl_xor(s1, off, 64);
        s2 += __shfl_xor(s2, off, 64);
      }
      const float mean = s1 * (1.f / 64.f);
      const float var  = fmaxf(s2 * (1.f / 64.f) - mean * mean, 0.f);
      const float rstd = rsqrtf(var + 1e-5f);
      #pragma unroll
      for (int et = 0; et < 4; et++)
        xr[16 * et + l16] = (y[et] - mean) * rstd * g1v[et] + b1v[et];
    }
  }
}

// ---------------- K3b: GI[t][seq][192] = x_ln1 @ Wih^T + bih  (fp16, parallel) ----------
__global__ __launch_bounds__(256) void k_gih(
    const float* __restrict__ x, const float* __restrict__ Wih,
    const float* __restrict__ bih, unsigned int* __restrict__ GI2)
{
  __shared__ unsigned int sW[192*32];   // 24KB packed half2 weights
  __shared__ unsigned int sbuf[256*33]; // overlay: x-stage [256][33], then out-stage [256][25]
  const int tid = threadIdx.x;
  const int b = blockIdx.x >> 7, t = blockIdx.x & 127;
  const float* xt = x + (((size_t)b * TT + t) * NN) * DD;

  for (int idx = tid; idx < 192*32; idx += 256) {
    float2 w = ((const float2*)Wih)[idx];
    half2_t h; h.x = (_Float16)w.x; h.y = (_Float16)w.y;
    sW[idx] = __builtin_bit_cast(unsigned int, h);
  }
  for (int idx = tid; idx < 256*32; idx += 256) {
    int n = idx >> 5, k = idx & 31;
    float2 v = ((const float2*)xt)[idx];
    half2_t h; h.x = (_Float16)v.x; h.y = (_Float16)v.y;
    sbuf[n*33 + k] = __builtin_bit_cast(unsigned int, h);
  }
  __syncthreads();
  half2_t xr[32];
  #pragma unroll
  for (int k = 0; k < 32; k++) xr[k] = __builtin_bit_cast(half2_t, sbuf[tid*33 + k]);
  __syncthreads();

  const size_t blockbase = ((size_t)t * 2048 + b * 256) * 96;  // dword index
  for (int c = 0; c < 4; c++) {
    #pragma unroll 2
    for (int j2 = 0; j2 < 24; j2++) {
      int e0 = c*48 + 2*j2;
      float a0 = bih[e0], a1 = bih[e0+1];
      const half8_t* w0 = (const half8_t*)(sW + e0*32);
      const half8_t* w1 = (const half8_t*)(sW + (e0+1)*32);
      #pragma unroll
      for (int kq = 0; kq < 8; kq++) {
        h8u ua, ub; ua.v = w0[kq]; ub.v = w1[kq];
        #pragma unroll
        for (int m = 0; m < 4; m++) {
          a0 = FDOT2(ua.h[m], xr[4*kq+m], a0);
          a1 = FDOT2(ub.h[m], xr[4*kq+m], a1);
        }
      }
      half2_t o; o.x = (_Float16)a0; o.y = (_Float16)a1;
      sbuf[tid*25 + j2] = __builtin_bit_cast(unsigned int, o);
    }
    __syncthreads();
    for (int idx = tid; idx < 6144; idx += 256) {
      int n = idx / 24, e2 = idx % 24;
      GI2[blockbase + (size_t)n*96 + c*24 + e2] = sbuf[n*25 + e2];
    }
    __syncthreads();
  }
}

// ---------------- K4: GRU over T, wave-per-sequence (no LDS, no barriers) ----------
// 512 blocks x 4 waves; wave w of block (b,n4) owns sequence (b, n4*4+w).
// Lane l owns dim d=l and gate rows {l, 64+l, 128+l} of Whh (f16-packed, 96 VGPRs).
// h broadcast via readlane of packed half2 (lanes 0..31 hold (h[2k],h[2k+1])).
__global__ __launch_bounds__(256, 2) void k_gru_gi(
    float* __restrict__ x, const _Float16* __restrict__ GIh,
    const float* __restrict__ Whh, const float* __restrict__ bhh,
    const float* __restrict__ g2, const float* __restrict__ b2)
{
  const int tid = threadIdx.x;
  const int w = tid >> 6;
  const int l = tid & 63;
  const int b = blockIdx.x >> 6, n4 = blockIdx.x & 63;

  // weights: rows l, 64+l, 128+l of Whh, packed half2
  half2_t wr[32], wz[32], wn[32];
  {
    const float2* Wr = (const float2*)(Whh + (size_t)l * 64);
    const float2* Wz = (const float2*)(Whh + (size_t)(64 + l) * 64);
    const float2* Wn = (const float2*)(Whh + (size_t)(128 + l) * 64);
    #pragma unroll
    for (int k = 0; k < 32; k++) {
      float2 a = Wr[k]; half2_t ha; ha.x = (_Float16)a.x; ha.y = (_Float16)a.y; wr[k] = ha;
      float2 c = Wz[k]; half2_t hc; hc.x = (_Float16)c.x; hc.y = (_Float16)c.y; wz[k] = hc;
      float2 e = Wn[k]; half2_t he; he.x = (_Float16)e.x; he.y = (_Float16)e.y; wn[k] = he;
    }
  }
  const float bhr = bhh[l], bhz = bhh[64 + l], bhn = bhh[128 + l];
  const float lng = g2[l], lnb = b2[l];

  float hreg = 0.f;
  unsigned int h2pack = 0;   // f16 pair (h[2k],h[2k+1]) in lane k<32; h=0 -> bits 0

  const size_t gistride = (size_t)2048 * 192;
  const size_t xstride  = (size_t)NN * DD;
  size_t gioff = ((size_t)b * 256 + n4 * 4 + w) * 192 + l;
  size_t xoff  = (((size_t)b * TT) * NN + n4 * 4 + w) * DD + l;

  // prefetch t=0
  float gir = (float)GIh[gioff];
  float giz = (float)GIh[gioff + 64];
  float gin = (float)GIh[gioff + 128];
  float xv  = x[xoff];

  const int li = l & 31;

  for (int t = 0; t < TT; t++) {
    // prefetch t+1 (clamped to stay in-bounds; discarded at t=127)
    const size_t adv = (t + 1 < TT) ? 1 : 0;
    const size_t gioff_n = gioff + adv * gistride;
    const size_t xoff_n  = xoff  + adv * xstride;
    float gir_n = (float)GIh[gioff_n];
    float giz_n = (float)GIh[gioff_n + 64];
    float gin_n = (float)GIh[gioff_n + 128];
    float xv_n  = x[xoff_n];

    // gh = Whh @ h  (readlane-broadcast dot2, no LDS, no barrier)
    float ar = bhr, az = bhz, an = bhn;
    #pragma unroll
    for (int k = 0; k < 32; k++) {
      half2_t s2 = __builtin_bit_cast(half2_t,
                     __builtin_amdgcn_readlane((int)h2pack, k));
      ar = FDOT2(wr[k], s2, ar);
      az = FDOT2(wz[k], s2, az);
      an = FDOT2(wn[k], s2, an);
    }

    const float r = 1.f / (1.f + __expf(-(gir + ar)));
    const float z = 1.f / (1.f + __expf(-(giz + az)));
    const float e = __expf(2.f * (gin + r * an));
    const float nt = 1.f - 2.f / (e + 1.f);     // tanh, overflow-safe
    const float hn = (1.f - z) * nt + z * hreg;
    hreg = hn;

    // residual + LN over the 64 lanes of this wave
    const float yv = xv + hn;
    float s1 = yv, s2v = yv * yv;
    #pragma unroll
    for (int off = 32; off > 0; off >>= 1) {
      s1  += __shfl_xor(s1,  off, 64);
      s2v += __shfl_xor(s2v, off, 64);
    }
    const float mean = s1 * 0.015625f;
    const float var  = fmaxf(s2v * 0.015625f - mean * mean, 0.f);
    const float hm = (yv - mean) * rsqrtf(var + 1e-5f) * lng + lnb;
    x[xoff] = xv + hm;

    // repack h for next step: lane k<32 gets (h[2k], h[2k+1])
    const float hae = __shfl(hn, 2 * li, 64);
    const float hbe = __shfl(hn, 2 * li + 1, 64);
    half2_t hp; hp.x = (_Float16)hae; hp.y = (_Float16)hbe;
    h2pack = __builtin_bit_cast(unsigned int, hp);

    gir = gir_n; giz = giz_n; gin = gin_n; xv = xv_n;
    gioff += gistride; xoff += xstride;
  }
}

// ---------------- K4 fallback: original fused GRU (ws too small for GI) ----------------
__global__ __launch_bounds__(256) void k_gru(
    float* __restrict__ x,
    const float* __restrict__ Wih, const float* __restrict__ Whh,
    const float* __restrict__ bih, const float* __restrict__ bhh,
    const float* __restrict__ g2, const float* __restrict__ b2)
{
  __shared__ half2_t sWi[192][33];
  __shared__ half2_t sWh[192][33];
  __shared__ float   xs[4][64];
  __shared__ half2_t xs_h[4][32];
  __shared__ float   hs_f[4][64];
  __shared__ half2_t hs_h[4][32];
  __shared__ float   gis[4][192];
  __shared__ float   ghs[4][192];

  const int b  = blockIdx.x >> 6;
  const int ng = blockIdx.x & 63;

  for (int idx = threadIdx.x; idx < 192 * 32; idx += 256) {
    int g = idx >> 5, dh = idx & 31;
    half2_t hv; hv.x = (_Float16)Wih[g*64 + 2*dh]; hv.y = (_Float16)Wih[g*64 + 2*dh + 1];
    sWi[g][dh] = hv;
    half2_t hw; hw.x = (_Float16)Whh[g*64 + 2*dh]; hw.y = (_Float16)Whh[g*64 + 2*dh + 1];
    sWh[g][dh] = hw;
  }
  const int s_d = threadIdx.x >> 6;
  const int d_d = threadIdx.x & 63;
  hs_f[s_d][d_d] = 0.f;
  ((_Float16*)hs_h[s_d])[d_d] = (_Float16)0.f;
  const float lng = g2[d_d], lnb = b2[d_d];

  int   tsk_s[3], tsk_g[3];
  float tb_i[3], tb_h[3];
  #pragma unroll
  for (int k = 0; k < 3; k++) {
    int task = threadIdx.x + k * 256;
    tsk_s[k] = task / 192; tsk_g[k] = task % 192;
    tb_i[k] = bih[tsk_g[k]]; tb_h[k] = bhh[tsk_g[k]];
  }
  __syncthreads();

  const size_t base = (((size_t)b * TT) * NN + ng * 4) * DD;
  for (int t = 0; t < TT; t++) {
    const size_t row = base + (size_t)t * NN * DD + s_d * 64 + d_d;
    float xv = x[row];
    xs[s_d][d_d] = xv;
    ((_Float16*)xs_h[s_d])[d_d] = (_Float16)xv;
    __syncthreads();

    #pragma unroll
    for (int k = 0; k < 3; k++) {
      int s = tsk_s[k], g = tsk_g[k];
      float ai = tb_i[k], ah = tb_h[k];
      #pragma unroll
      for (int dh = 0; dh < 32; dh++) {
        ai = FDOT2(sWi[g][dh], xs_h[s][dh], ai);
        ah = FDOT2(sWh[g][dh], hs_h[s][dh], ah);
      }
      gis[s][g] = ai; ghs[s][g] = ah;
    }
    __syncthreads();

    float gr = gis[s_d][d_d]      + ghs[s_d][d_d];
    float gz = gis[s_d][64 + d_d] + ghs[s_d][64 + d_d];
    float r  = 1.f / (1.f + __expf(-gr));
    float z  = 1.f / (1.f + __expf(-gz));
    float nn = tanhf(gis[s_d][128 + d_d] + r * ghs[s_d][128 + d_d]);
    float ho = hs_f[s_d][d_d];
    float hn = (1.f - z) * nn + z * ho;

    float yv = xs[s_d][d_d] + hn;
    float s1 = yv, s2 = yv * yv;
    #pragma unroll
    for (int off = 32; off > 0; off >>= 1) {
      s1 += __shfl_xor(s1, off, 64);
      s2 += __shfl_xor(s2, off, 64);
    }
    float mean = s1 * (1.f / 64.f);
    float var  = fmaxf(s2 * (1.f / 64.f) - mean * mean, 0.f);
    float hm = (yv - mean) * rsqrtf(var + 1e-5f) * lng + lnb;

    x[row] = xs[s_d][d_d] + hm;
    hs_f[s_d][d_d] = hn;
    ((_Float16*)hs_h[s_d])[d_d] = (_Float16)hn;
    __syncthreads();
  }
}

extern "C" void kernel_launch(void* const* d_in, const int* in_sizes, int n_in,
                              void* d_out, int out_size, void* d_ws, size_t ws_size,
                              hipStream_t stream) {
  const float* Hi  = (const float*)d_in[0];
  const float* Hj  = (const float*)d_in[1];
  const float* Wq  = (const float*)d_in[2];  const float* bq = (const float*)d_in[3];
  const float* Wk  = (const float*)d_in[4];  const float* bk = (const float*)d_in[5];
  const float* Wv  = (const float*)d_in[6];  const float* bv = (const float*)d_in[7];
  const float* lg  = (const float*)d_in[8];  const float* lt = (const float*)d_in[9];
  const float* e1  = (const float*)d_in[10]; const float* e2 = (const float*)d_in[11];
  const float* Wg  = (const float*)d_in[12]; const float* bg = (const float*)d_in[13];
  const float* g1  = (const float*)d_in[14]; const float* b1 = (const float*)d_in[15];
  const float* Wih = (const float*)d_in[16]; const float* Whh = (const float*)d_in[17];
  const float* bih = (const float*)d_in[18]; const float* bhh = (const float*)d_in[19];
  const float* g2  = (const float*)d_in[20]; const float* b2  = (const float*)d_in[21];
  float* out  = (float*)d_out;

  unsigned short* adph = (unsigned short*)d_ws;        // 128KB @ offset 0 (f16 adjacency)
  unsigned int* wg2 = (unsigned int*)d_ws + 32768;     // 8KB @ offset 128KB
  unsigned int* wq2 = (unsigned int*)d_ws + 65536;     // 3 x 8KB @ offset 256KB
  unsigned int* wk2 = wq2 + 2048;
  unsigned int* wv2 = wk2 + 2048;
  const size_t gi_off = 286720;                        // byte offset, 512-aligned
  const size_t gi_bytes = (size_t)2048 * TT * 192 * 2; // 96MB fp16
  const bool use_gi = ws_size >= gi_off + gi_bytes;
  unsigned int* GI2 = (unsigned int*)((char*)d_ws + gi_off);
  _Float16*     GIh = (_Float16*)((char*)d_ws + gi_off);

  k_prep<<<dim3(8),     dim3(256), 0, stream>>>(Wq, Wk, Wv, Wg, wq2, wk2, wv2, wg2);
  k_attn<<<dim3(BB*NN), dim3(256), 0, stream>>>(Hi, Hj, wq2, wk2, wv2, bq, bk, bv, lg, lt, out);
  k_adp <<<dim3(NN),    dim3(256), 0, stream>>>(e1, e2, adph);
  k_gcn <<<dim3(BB*TT), dim3(256), 0, stream>>>(out, adph, wg2, bg, g1, b1);
  if (use_gi) {
    k_gih   <<<dim3(BB*TT), dim3(256), 0, stream>>>(out, Wih, bih, GI2);
    k_gru_gi<<<dim3(512),   dim3(256), 0, stream>>>(out, GIh, Whh, bhh, g2, b2);
  } else {
    k_gru   <<<dim3(512),   dim3(256), 0, stream>>>(out, Wih, Whh, bih, bhh, g2, b2);
  }
}

// Round 6
// 521.625 us; speedup vs baseline: 1.9923x; 1.0544x over previous
//
#include <hip/hip_runtime.h>
#include <cstddef>

#define BB 8
#define TT 128
#define NN 256
#define DD 64

typedef _Float16 half2_t __attribute__((ext_vector_type(2)));
typedef _Float16 half4_t __attribute__((ext_vector_type(4)));
typedef _Float16 half8_t __attribute__((ext_vector_type(8)));
typedef float f32x4 __attribute__((ext_vector_type(4)));

#if defined(__has_builtin)
#  if __has_builtin(__builtin_amdgcn_fdot2)
#    define FDOT2(a,b,c) __builtin_amdgcn_fdot2((a),(b),(c),false)
#  endif
#endif
#ifndef FDOT2
#  define FDOT2(a,b,c) ((c) + (float)(a).x*(float)(b).x + (float)(a).y*(float)(b).y)
#endif

union h8u { half8_t v; half2_t h[4]; };

// wave64 sum via DPP row_shr tree (VALU-only; no DS-pipe waits)
__device__ __forceinline__ float wave64_sum(float x) {
#if defined(__has_builtin) && __has_builtin(__builtin_amdgcn_update_dpp)
  int t;
  t = __builtin_amdgcn_update_dpp(0, __builtin_bit_cast(int, x), 0x111, 0xF, 0xF, true);
  x += __builtin_bit_cast(float, t);
  t = __builtin_amdgcn_update_dpp(0, __builtin_bit_cast(int, x), 0x112, 0xF, 0xF, true);
  x += __builtin_bit_cast(float, t);
  t = __builtin_amdgcn_update_dpp(0, __builtin_bit_cast(int, x), 0x114, 0xF, 0xF, true);
  x += __builtin_bit_cast(float, t);
  t = __builtin_amdgcn_update_dpp(0, __builtin_bit_cast(int, x), 0x118, 0xF, 0xF, true);
  x += __builtin_bit_cast(float, t);
  // lanes 15,31,47,63 hold their 16-lane group sums
  float g0 = __builtin_bit_cast(float, __builtin_amdgcn_readlane(__builtin_bit_cast(int, x), 15));
  float g1 = __builtin_bit_cast(float, __builtin_amdgcn_readlane(__builtin_bit_cast(int, x), 31));
  float g2 = __builtin_bit_cast(float, __builtin_amdgcn_readlane(__builtin_bit_cast(int, x), 47));
  float g3 = __builtin_bit_cast(float, __builtin_amdgcn_readlane(__builtin_bit_cast(int, x), 63));
  return (g0 + g1) + (g2 + g3);
#else
  #pragma unroll
  for (int off = 32; off > 0; off >>= 1) x += __shfl_xor(x, off, 64);
  return x;
#endif
}

// ---------------- K0: pack W matrices to half2 in ws ----------------
__global__ __launch_bounds__(256) void k_prep(
    const float* __restrict__ Wq, const float* __restrict__ Wk, const float* __restrict__ Wv,
    const float* __restrict__ Wg,
    unsigned int* __restrict__ wq2, unsigned int* __restrict__ wk2,
    unsigned int* __restrict__ wv2, unsigned int* __restrict__ wg2)
{
  int t = blockIdx.x * 256 + threadIdx.x;
  if (t < 2048) {
    half2_t a; a.x = (_Float16)Wq[2*t]; a.y = (_Float16)Wq[2*t+1];
    wq2[t] = __builtin_bit_cast(unsigned int, a);
    half2_t b; b.x = (_Float16)Wk[2*t]; b.y = (_Float16)Wk[2*t+1];
    wk2[t] = __builtin_bit_cast(unsigned int, b);
    half2_t c; c.x = (_Float16)Wv[2*t]; c.y = (_Float16)Wv[2*t+1];
    wv2[t] = __builtin_bit_cast(unsigned int, c);
    half2_t d; d.x = (_Float16)Wg[2*t]; d.y = (_Float16)Wg[2*t+1];
    wg2[t] = __builtin_bit_cast(unsigned int, d);
  }
}

// ---------------- K1: MFMA fused QKV + per-(b,n) temporal attention ----------------
#define KSTR 72    // sK row stride (f16)
#define PSTR 136   // sVt / sP row stride (f16)

__device__ __forceinline__ half8_t wfrag(const unsigned int* __restrict__ W2, int e, int k0) {
  return *(const half8_t*)(W2 + e * 32 + (k0 >> 1));
}

__global__ __launch_bounds__(256, 2) void k_attn(
    const float* __restrict__ Hi, const float* __restrict__ Hj,
    const unsigned int* __restrict__ wq2, const unsigned int* __restrict__ wk2,
    const unsigned int* __restrict__ wv2,
    const float* __restrict__ bq, const float* __restrict__ bk, const float* __restrict__ bv,
    const float* __restrict__ lgp, const float* __restrict__ ltp,
    float* __restrict__ out)
{
  __shared__ __align__(16) _Float16 sK[TT][KSTR];
  __shared__ __align__(16) _Float16 sVt[DD][PSTR];
  __shared__ __align__(16) _Float16 sP[4][32][PSTR];
  __shared__ float sDecay[TT];

  const int b   = blockIdx.x >> 8;
  const int n   = blockIdx.x & 255;
  const int tid = threadIdx.x;
  const int w   = tid >> 6;
  const int l   = tid & 63;
  const int l16 = l & 15;
  const int lg4 = l >> 4;

  const float gamma = fmaxf(__expf(lgp[0]), 0.01f);
  const float tau   = fmaxf(__expf(ltp[0]), 0.01f);
  const float scale = 1.0f / (8.0f * tau);
  if (tid < TT) {
    float dt = gamma * (float)tid * (1.0f / 127.0f);
    sDecay[tid] = __logf(__expf(-dt) + 1e-8f);
  }

  const int row0 = 32 * w;
  half8_t hai[2][2], haj[2][2];
  #pragma unroll
  for (int mt = 0; mt < 2; mt++) {
    const int i = row0 + 16 * mt + l16;
    const float* ri = Hi + (((size_t)b * TT + i) * NN + n) * DD;
    const float* rj = Hj + (((size_t)b * TT + i) * NN + n) * DD;
    #pragma unroll
    for (int ks = 0; ks < 2; ks++) {
      const int k0 = 32 * ks + 8 * lg4;
      float4 a = *(const float4*)(ri + k0);
      float4 c = *(const float4*)(ri + k0 + 4);
      half8_t h;
      h[0]=(_Float16)a.x; h[1]=(_Float16)a.y; h[2]=(_Float16)a.z; h[3]=(_Float16)a.w;
      h[4]=(_Float16)c.x; h[5]=(_Float16)c.y; h[6]=(_Float16)c.z; h[7]=(_Float16)c.w;
      hai[mt][ks] = h;
      a = *(const float4*)(rj + k0);
      c = *(const float4*)(rj + k0 + 4);
      h[0]=(_Float16)a.x; h[1]=(_Float16)a.y; h[2]=(_Float16)a.z; h[3]=(_Float16)a.w;
      h[4]=(_Float16)c.x; h[5]=(_Float16)c.y; h[6]=(_Float16)c.z; h[7]=(_Float16)c.w;
      haj[mt][ks] = h;
    }
  }

  #pragma unroll
  for (int nt = 0; nt < 4; nt++) {
    const int e = 16 * nt + l16;
    half8_t wb0 = wfrag(wq2, e, 8 * lg4);
    half8_t wb1 = wfrag(wq2, e, 32 + 8 * lg4);
    const float be = bq[e];
    #pragma unroll
    for (int mt = 0; mt < 2; mt++) {
      f32x4 acc = {be, be, be, be};
      acc = __builtin_amdgcn_mfma_f32_16x16x32_f16(hai[mt][0], wb0, acc, 0, 0, 0);
      acc = __builtin_amdgcn_mfma_f32_16x16x32_f16(hai[mt][1], wb1, acc, 0, 0, 0);
      #pragma unroll
      for (int r = 0; r < 4; r++)
        sP[w][16 * mt + 4 * lg4 + r][e] = (_Float16)(acc[r] * scale);
    }
  }

  #pragma unroll
  for (int nt = 0; nt < 4; nt++) {
    const int e = 16 * nt + l16;
    half8_t wb0 = wfrag(wk2, e, 8 * lg4);
    half8_t wb1 = wfrag(wk2, e, 32 + 8 * lg4);
    const float be = bk[e];
    #pragma unroll
    for (int mt = 0; mt < 2; mt++) {
      f32x4 acc = {be, be, be, be};
      acc = __builtin_amdgcn_mfma_f32_16x16x32_f16(haj[mt][0], wb0, acc, 0, 0, 0);
      acc = __builtin_amdgcn_mfma_f32_16x16x32_f16(haj[mt][1], wb1, acc, 0, 0, 0);
      #pragma unroll
      for (int r = 0; r < 4; r++)
        sK[row0 + 16 * mt + 4 * lg4 + r][e] = (_Float16)acc[r];
    }
  }

  #pragma unroll
  for (int nt = 0; nt < 4; nt++) {
    const int e = 16 * nt + l16;
    half8_t wb0 = wfrag(wv2, e, 8 * lg4);
    half8_t wb1 = wfrag(wv2, e, 32 + 8 * lg4);
    const float be = bv[e];
    #pragma unroll
    for (int mt = 0; mt < 2; mt++) {
      f32x4 acc = {be, be, be, be};
      acc = __builtin_amdgcn_mfma_f32_16x16x32_f16(haj[mt][0], wb0, acc, 0, 0, 0);
      acc = __builtin_amdgcn_mfma_f32_16x16x32_f16(haj[mt][1], wb1, acc, 0, 0, 0);
      const int jb = row0 + 16 * mt + 4 * lg4;
      half4_t v4;
      v4[0] = (_Float16)acc[0]; v4[1] = (_Float16)acc[1];
      v4[2] = (_Float16)acc[2]; v4[3] = (_Float16)acc[3];
      *(half4_t*)(&sVt[e][jb]) = v4;
    }
  }
  __syncthreads();

  half8_t qa[2][2];
  #pragma unroll
  for (int mt = 0; mt < 2; mt++)
    #pragma unroll
    for (int ks = 0; ks < 2; ks++)
      qa[mt][ks] = *(const half8_t*)(&sP[w][16 * mt + l16][32 * ks + 8 * lg4]);

  float rs[2][4] = {{0.f,0.f,0.f,0.f},{0.f,0.f,0.f,0.f}};
  for (int jt = 0; jt < 8; jt++) {
    const int j = 16 * jt + l16;
    half8_t kb0 = *(const half8_t*)(&sK[j][8 * lg4]);
    half8_t kb1 = *(const half8_t*)(&sK[j][32 + 8 * lg4]);
    #pragma unroll
    for (int mt = 0; mt < 2; mt++) {
      f32x4 acc = {0.f, 0.f, 0.f, 0.f};
      acc = __builtin_amdgcn_mfma_f32_16x16x32_f16(qa[mt][0], kb0, acc, 0, 0, 0);
      acc = __builtin_amdgcn_mfma_f32_16x16x32_f16(qa[mt][1], kb1, acc, 0, 0, 0);
      #pragma unroll
      for (int r = 0; r < 4; r++) {
        const int il = 16 * mt + 4 * lg4 + r;
        int di = (row0 + il) - j; di = di < 0 ? -di : di;
        float p = __expf(acc[r] + sDecay[di]);
        rs[mt][r] += p;
        sP[w][il][j] = (_Float16)p;
      }
    }
  }

  f32x4 oacc[2][4] = {};
  #pragma unroll
  for (int ks = 0; ks < 4; ks++) {
    const int j0 = 32 * ks + 8 * lg4;
    half8_t pa0 = *(const half8_t*)(&sP[w][l16][j0]);
    half8_t pa1 = *(const half8_t*)(&sP[w][16 + l16][j0]);
    #pragma unroll
    for (int nt = 0; nt < 4; nt++) {
      half8_t vb = *(const half8_t*)(&sVt[16 * nt + l16][j0]);
      oacc[0][nt] = __builtin_amdgcn_mfma_f32_16x16x32_f16(pa0, vb, oacc[0][nt], 0, 0, 0);
      oacc[1][nt] = __builtin_amdgcn_mfma_f32_16x16x32_f16(pa1, vb, oacc[1][nt], 0, 0, 0);
    }
  }

  #pragma unroll
  for (int mt = 0; mt < 2; mt++)
    #pragma unroll
    for (int r = 0; r < 4; r++) {
      float v = rs[mt][r];
      v += __shfl_xor(v, 1, 64);
      v += __shfl_xor(v, 2, 64);
      v += __shfl_xor(v, 4, 64);
      v += __shfl_xor(v, 8, 64);
      rs[mt][r] = 1.0f / v;
    }
  #pragma unroll
  for (int mt = 0; mt < 2; mt++) {
    #pragma unroll
    for (int r = 0; r < 4; r++) {
      const int i = row0 + 16 * mt + 4 * lg4 + r;
      float* orow = out + (((size_t)b * TT + i) * NN + n) * DD;
      const float rl = rs[mt][r];
      #pragma unroll
      for (int nt = 0; nt < 4; nt++)
        orow[16 * nt + l16] = oacc[mt][nt][r] * rl;
    }
  }
}

// ---------------- K2: adjacency adph[m][n] = softmax_row_m(relu(e1@e2)) in f16 --------
__global__ __launch_bounds__(256) void k_adp(
    const float* __restrict__ e1, const float* __restrict__ e2,
    unsigned short* __restrict__ adph)
{
  const int m = blockIdx.x, n = threadIdx.x;
  float s = 0.f;
  #pragma unroll
  for (int k = 0; k < 32; k++) s += e1[m*32+k] * e2[k*256+n];
  s = fmaxf(s, 0.f);
  __shared__ float red[256];
  red[n] = s; __syncthreads();
  for (int off = 128; off > 0; off >>= 1) {
    if (n < off) red[n] = fmaxf(red[n], red[n+off]);
    __syncthreads();
  }
  float mx = red[0];
  __syncthreads();
  float p = __expf(s - mx);
  red[n] = p; __syncthreads();
  for (int off = 128; off > 0; off >>= 1) {
    if (n < off) red[n] += red[n+off];
    __syncthreads();
  }
  _Float16 h = (_Float16)(p / red[0]);
  adph[m*256 + n] = __builtin_bit_cast(unsigned short, h);
}

// ---------------- K3: MFMA GCN + residual + LN1 (in-place on x) ----------------
#define GSTR 280   // f16 row stride for sxhT / sgT (560 B, 16B-aligned)

__global__ __launch_bounds__(256, 2) void k_gcn(
    float* __restrict__ x, const unsigned short* __restrict__ adph,
    const unsigned int* __restrict__ wg2, const float* __restrict__ bg,
    const float* __restrict__ g1, const float* __restrict__ b1)
{
  __shared__ __align__(16) _Float16 sxhT[DD][GSTR];
  __shared__ __align__(16) _Float16 sgT[DD][GSTR];

  const int tid = threadIdx.x;
  const int w   = tid >> 6;
  const int l   = tid & 63;
  const int l16 = l & 15;
  const int lg4 = l >> 4;
  float* tile = x + (size_t)blockIdx.x * NN * DD;

  {
    const int d2 = tid & 31;
    const int mg = tid >> 5;
    #pragma unroll
    for (int it = 0; it < 16; it++) {
      const int m0 = mg * 2 + it * 16;
      float2 va = *(const float2*)(tile + (size_t)m0 * DD + 2 * d2);
      float2 vb = *(const float2*)(tile + (size_t)(m0 + 1) * DD + 2 * d2);
      half2_t h0; h0.x = (_Float16)va.x; h0.y = (_Float16)vb.x;
      half2_t h1; h1.x = (_Float16)va.y; h1.y = (_Float16)vb.y;
      *(half2_t*)(&sxhT[2 * d2][m0])     = h0;
      *(half2_t*)(&sxhT[2 * d2 + 1][m0]) = h1;
    }
  }
  __syncthreads();

  f32x4 acc1[4][4] = {};
  for (int ks = 0; ks < 8; ks++) {
    const int k0 = 32 * ks + 8 * lg4;
    half8_t bfr[4], afr[4];
    #pragma unroll
    for (int nt = 0; nt < 4; nt++)
      bfr[nt] = *(const half8_t*)(&sxhT[16 * nt + l16][k0]);
    #pragma unroll
    for (int mt = 0; mt < 4; mt++) {
      const int m = 64 * w + 16 * mt + l16;
      afr[mt] = *(const half8_t*)(adph + m * 256 + k0);
    }
    #pragma unroll
    for (int mt = 0; mt < 4; mt++)
      #pragma unroll
      for (int nt = 0; nt < 4; nt++)
        acc1[mt][nt] = __builtin_amdgcn_mfma_f32_16x16x32_f16(afr[mt], bfr[nt], acc1[mt][nt], 0, 0, 0);
  }

  #pragma unroll
  for (int mt = 0; mt < 4; mt++)
    #pragma unroll
    for (int nt = 0; nt < 4; nt++) {
      half4_t g4;
      g4[0] = (_Float16)acc1[mt][nt][0]; g4[1] = (_Float16)acc1[mt][nt][1];
      g4[2] = (_Float16)acc1[mt][nt][2]; g4[3] = (_Float16)acc1[mt][nt][3];
      *(half4_t*)(&sgT[16 * nt + l16][64 * w + 16 * mt + 4 * lg4]) = g4;
    }
  __syncthreads();

  half8_t wb[4][2];
  float bgv[4], g1v[4], b1v[4];
  #pragma unroll
  for (int et = 0; et < 4; et++) {
    const int e = 16 * et + l16;
    wb[et][0] = wfrag(wg2, e, 8 * lg4);
    wb[et][1] = wfrag(wg2, e, 32 + 8 * lg4);
    bgv[et] = bg[e]; g1v[et] = g1[e]; b1v[et] = b1[e];
  }

  #pragma unroll 1
  for (int mt = 0; mt < 4; mt++) {
    half8_t ga[2];
    #pragma unroll
    for (int ks = 0; ks < 2; ks++) {
      half8_t h;
      #pragma unroll
      for (int j = 0; j < 8; j++)
        h[j] = sgT[32 * ks + 8 * lg4 + j][64 * w + 16 * mt + l16];
      ga[ks] = h;
    }
    f32x4 acc2[4];
    #pragma unroll
    for (int et = 0; et < 4; et++) {
      f32x4 a = {bgv[et], bgv[et], bgv[et], bgv[et]};
      a = __builtin_amdgcn_mfma_f32_16x16x32_f16(ga[0], wb[et][0], a, 0, 0, 0);
      a = __builtin_amdgcn_mfma_f32_16x16x32_f16(ga[1], wb[et][1], a, 0, 0, 0);
      acc2[et] = a;
    }
    #pragma unroll
    for (int r = 0; r < 4; r++) {
      const int mrow = 64 * w + 16 * mt + 4 * lg4 + r;
      float* xr = tile + (size_t)mrow * DD;
      float y[4], s1 = 0.f, s2 = 0.f;
      #pragma unroll
      for (int et = 0; et < 4; et++) {
        float h = fmaxf(acc2[et][r], 0.f);
        float yv = xr[16 * et + l16] + h;
        y[et] = yv; s1 += yv; s2 += yv * yv;
      }
      #pragma unroll
      for (int off = 1; off < 16; off <<= 1) {
        s1 += __shfl_xor(s1, off, 64);
        s2 += __shfl_xor(s2, off, 64);
      }
      const float mean = s1 * (1.f / 64.f);
      const float var  = fmaxf(s2 * (1.f / 64.f) - mean * mean, 0.f);
      const float rstd = rsqrtf(var + 1e-5f);
      #pragma unroll
      for (int et = 0; et < 4; et++)
        xr[16 * et + l16] = (y[et] - mean) * rstd * g1v[et] + b1v[et];
    }
  }
}

// ---------------- K3b: GI[t][seq][192] = x_ln1 @ Wih^T + bih  (fp16, parallel) ----------
__global__ __launch_bounds__(256) void k_gih(
    const float* __restrict__ x, const float* __restrict__ Wih,
    const float* __restrict__ bih, unsigned int* __restrict__ GI2)
{
  __shared__ unsigned int sW[192*32];
  __shared__ unsigned int sbuf[256*33];
  const int tid = threadIdx.x;
  const int b = blockIdx.x >> 7, t = blockIdx.x & 127;
  const float* xt = x + (((size_t)b * TT + t) * NN) * DD;

  for (int idx = tid; idx < 192*32; idx += 256) {
    float2 w = ((const float2*)Wih)[idx];
    half2_t h; h.x = (_Float16)w.x; h.y = (_Float16)w.y;
    sW[idx] = __builtin_bit_cast(unsigned int, h);
  }
  for (int idx = tid; idx < 256*32; idx += 256) {
    int n = idx >> 5, k = idx & 31;
    float2 v = ((const float2*)xt)[idx];
    half2_t h; h.x = (_Float16)v.x; h.y = (_Float16)v.y;
    sbuf[n*33 + k] = __builtin_bit_cast(unsigned int, h);
  }
  __syncthreads();
  half2_t xr[32];
  #pragma unroll
  for (int k = 0; k < 32; k++) xr[k] = __builtin_bit_cast(half2_t, sbuf[tid*33 + k]);
  __syncthreads();

  const size_t blockbase = ((size_t)t * 2048 + b * 256) * 96;  // dword index
  for (int c = 0; c < 4; c++) {
    #pragma unroll 2
    for (int j2 = 0; j2 < 24; j2++) {
      int e0 = c*48 + 2*j2;
      float a0 = bih[e0], a1 = bih[e0+1];
      const half8_t* w0 = (const half8_t*)(sW + e0*32);
      const half8_t* w1 = (const half8_t*)(sW + (e0+1)*32);
      #pragma unroll
      for (int kq = 0; kq < 8; kq++) {
        h8u ua, ub; ua.v = w0[kq]; ub.v = w1[kq];
        #pragma unroll
        for (int m = 0; m < 4; m++) {
          a0 = FDOT2(ua.h[m], xr[4*kq+m], a0);
          a1 = FDOT2(ub.h[m], xr[4*kq+m], a1);
        }
      }
      half2_t o; o.x = (_Float16)a0; o.y = (_Float16)a1;
      sbuf[tid*25 + j2] = __builtin_bit_cast(unsigned int, o);
    }
    __syncthreads();
    for (int idx = tid; idx < 6144; idx += 256) {
      int n = idx / 24, e2 = idx % 24;
      GI2[blockbase + (size_t)n*96 + c*24 + e2] = sbuf[n*25 + e2];
    }
    __syncthreads();
  }
}

// ---------------- K4: GRU over T, wave-per-sequence (DPP LN, 1 shfl/t) ----------
// Lane l owns dim d=l and gate rows {l, 64+l, 128+l} of Whh.
// h2pack lane k (k<32): (h[k], h[k+32]); weights packed to match: wX[k]=(W[row][k],W[row][k+32]).
__global__ __launch_bounds__(256, 2) void k_gru_gi(
    float* __restrict__ x, const _Float16* __restrict__ GIh,
    const float* __restrict__ Whh, const float* __restrict__ bhh,
    const float* __restrict__ g2, const float* __restrict__ b2)
{
  const int tid = threadIdx.x;
  const int w = tid >> 6;
  const int l = tid & 63;
  const int b = blockIdx.x >> 6, n4 = blockIdx.x & 63;

  half2_t wr[32], wz[32], wn[32];
  {
    float2 tmp[32];
    const float2* W0 = (const float2*)(Whh + (size_t)l * 64);
    #pragma unroll
    for (int q = 0; q < 32; q++) tmp[q] = W0[q];
    #pragma unroll
    for (int k = 0; k < 32; k++) {
      float lo = (k & 1) ? tmp[k >> 1].y : tmp[k >> 1].x;
      float hi = (k & 1) ? tmp[16 + (k >> 1)].y : tmp[16 + (k >> 1)].x;
      half2_t h; h.x = (_Float16)lo; h.y = (_Float16)hi; wr[k] = h;
    }
    const float2* W1 = (const float2*)(Whh + (size_t)(64 + l) * 64);
    #pragma unroll
    for (int q = 0; q < 32; q++) tmp[q] = W1[q];
    #pragma unroll
    for (int k = 0; k < 32; k++) {
      float lo = (k & 1) ? tmp[k >> 1].y : tmp[k >> 1].x;
      float hi = (k & 1) ? tmp[16 + (k >> 1)].y : tmp[16 + (k >> 1)].x;
      half2_t h; h.x = (_Float16)lo; h.y = (_Float16)hi; wz[k] = h;
    }
    const float2* W2 = (const float2*)(Whh + (size_t)(128 + l) * 64);
    #pragma unroll
    for (int q = 0; q < 32; q++) tmp[q] = W2[q];
    #pragma unroll
    for (int k = 0; k < 32; k++) {
      float lo = (k & 1) ? tmp[k >> 1].y : tmp[k >> 1].x;
      float hi = (k & 1) ? tmp[16 + (k >> 1)].y : tmp[16 + (k >> 1)].x;
      half2_t h; h.x = (_Float16)lo; h.y = (_Float16)hi; wn[k] = h;
    }
  }
  const float bhr = bhh[l], bhz = bhh[64 + l], bhn = bhh[128 + l];
  const float lng = g2[l], lnb = b2[l];

  float hreg = 0.f;
  unsigned int h2pack = 0;   // (h[k], h[k+32]) f16 pair in lane k<32; h=0 -> bits 0

  const size_t gistride = (size_t)2048 * 192;
  const size_t xstride  = (size_t)NN * DD;
  size_t gioff = ((size_t)b * 256 + n4 * 4 + w) * 192 + l;
  size_t xoff  = (((size_t)b * TT) * NN + n4 * 4 + w) * DD + l;

  // prefetch t=0
  float gir = (float)GIh[gioff];
  float giz = (float)GIh[gioff + 64];
  float gin = (float)GIh[gioff + 128];
  float xv  = x[xoff];

  for (int t = 0; t < TT; t++) {
    // prefetch t+1 (clamped; discarded at t=127)
    const size_t adv = (t + 1 < TT) ? 1 : 0;
    const size_t gioff_n = gioff + adv * gistride;
    const size_t xoff_n  = xoff  + adv * xstride;
    float gir_n = (float)GIh[gioff_n];
    float giz_n = (float)GIh[gioff_n + 64];
    float gin_n = (float)GIh[gioff_n + 128];
    float xv_n  = x[xoff_n];

    // gh = Whh @ h  (readlane-broadcast dot2)
    float ar = bhr, az = bhz, an = bhn;
    #pragma unroll
    for (int k = 0; k < 32; k++) {
      half2_t s2 = __builtin_bit_cast(half2_t,
                     __builtin_amdgcn_readlane((int)h2pack, k));
      ar = FDOT2(wr[k], s2, ar);
      az = FDOT2(wz[k], s2, az);
      an = FDOT2(wn[k], s2, an);
    }

    const float r = 1.f / (1.f + __expf(-(gir + ar)));
    const float z = 1.f / (1.f + __expf(-(giz + az)));
    const float e = __expf(2.f * (gin + r * an));
    const float nt = 1.f - 2.f / (e + 1.f);     // tanh, overflow-safe
    const float hn = (1.f - z) * nt + z * hreg;
    hreg = hn;

    // repack FIRST (critical path): one half-swap exchange
    const float other = __shfl_xor(hn, 32, 64);
    const float plo = (l < 32) ? hn : other;
    const float phi = (l < 32) ? other : hn;
    half2_t hp; hp.x = (_Float16)plo; hp.y = (_Float16)phi;
    h2pack = __builtin_bit_cast(unsigned int, hp);

    // LN via DPP (VALU-only) — off the recurrence path
    const float yv = xv + hn;
    const float s1  = wave64_sum(yv);
    const float s2v = wave64_sum(yv * yv);
    const float mean = s1 * 0.015625f;
    const float var  = fmaxf(s2v * 0.015625f - mean * mean, 0.f);
    const float hm = (yv - mean) * rsqrtf(var + 1e-5f) * lng + lnb;
    x[xoff] = xv + hm;

    gir = gir_n; giz = giz_n; gin = gin_n; xv = xv_n;
    gioff += gistride; xoff += xstride;
  }
}

// ---------------- K4 fallback: original fused GRU (ws too small for GI) ----------------
__global__ __launch_bounds__(256) void k_gru(
    float* __restrict__ x,
    const float* __restrict__ Wih, const float* __restrict__ Whh,
    const float* __restrict__ bih, const float* __restrict__ bhh,
    const float* __restrict__ g2, const float* __restrict__ b2)
{
  __shared__ half2_t sWi[192][33];
  __shared__ half2_t sWh[192][33];
  __shared__ float   xs[4][64];
  __shared__ half2_t xs_h[4][32];
  __shared__ float   hs_f[4][64];
  __shared__ half2_t hs_h[4][32];
  __shared__ float   gis[4][192];
  __shared__ float   ghs[4][192];

  const int b  = blockIdx.x >> 6;
  const int ng = blockIdx.x & 63;

  for (int idx = threadIdx.x; idx < 192 * 32; idx += 256) {
    int g = idx >> 5, dh = idx & 31;
    half2_t hv; hv.x = (_Float16)Wih[g*64 + 2*dh]; hv.y = (_Float16)Wih[g*64 + 2*dh + 1];
    sWi[g][dh] = hv;
    half2_t hw; hw.x = (_Float16)Whh[g*64 + 2*dh]; hw.y = (_Float16)Whh[g*64 + 2*dh + 1];
    sWh[g][dh] = hw;
  }
  const int s_d = threadIdx.x >> 6;
  const int d_d = threadIdx.x & 63;
  hs_f[s_d][d_d] = 0.f;
  ((_Float16*)hs_h[s_d])[d_d] = (_Float16)0.f;
  const float lng = g2[d_d], lnb = b2[d_d];

  int   tsk_s[3], tsk_g[3];
  float tb_i[3], tb_h[3];
  #pragma unroll
  for (int k = 0; k < 3; k++) {
    int task = threadIdx.x + k * 256;
    tsk_s[k] = task / 192; tsk_g[k] = task % 192;
    tb_i[k] = bih[tsk_g[k]]; tb_h[k] = bhh[tsk_g[k]];
  }
  __syncthreads();

  const size_t base = (((size_t)b * TT) * NN + ng * 4) * DD;
  for (int t = 0; t < TT; t++) {
    const size_t row = base + (size_t)t * NN * DD + s_d * 64 + d_d;
    float xv = x[row];
    xs[s_d][d_d] = xv;
    ((_Float16*)xs_h[s_d])[d_d] = (_Float16)xv;
    __syncthreads();

    #pragma unroll
    for (int k = 0; k < 3; k++) {
      int s = tsk_s[k], g = tsk_g[k];
      float ai = tb_i[k], ah = tb_h[k];
      #pragma unroll
      for (int dh = 0; dh < 32; dh++) {
        ai = FDOT2(sWi[g][dh], xs_h[s][dh], ai);
        ah = FDOT2(sWh[g][dh], hs_h[s][dh], ah);
      }
      gis[s][g] = ai; ghs[s][g] = ah;
    }
    __syncthreads();

    float gr = gis[s_d][d_d]      + ghs[s_d][d_d];
    float gz = gis[s_d][64 + d_d] + ghs[s_d][64 + d_d];
    float r  = 1.f / (1.f + __expf(-gr));
    float z  = 1.f / (1.f + __expf(-gz));
    float nn = tanhf(gis[s_d][128 + d_d] + r * ghs[s_d][128 + d_d]);
    float ho = hs_f[s_d][d_d];
    float hn = (1.f - z) * nn + z * ho;

    float yv = xs[s_d][d_d] + hn;
    float s1 = yv, s2 = yv * yv;
    #pragma unroll
    for (int off = 32; off > 0; off >>= 1) {
      s1 += __shfl_xor(s1, off, 64);
      s2 += __shfl_xor(s2, off, 64);
    }
    float mean = s1 * (1.f / 64.f);
    float var  = fmaxf(s2 * (1.f / 64.f) - mean * mean, 0.f);
    float hm = (yv - mean) * rsqrtf(var + 1e-5f) * lng + lnb;

    x[row] = xs[s_d][d_d] + hm;
    hs_f[s_d][d_d] = hn;
    ((_Float16*)hs_h[s_d])[d_d] = (_Float16)hn;
    __syncthreads();
  }
}

extern "C" void kernel_launch(void* const* d_in, const int* in_sizes, int n_in,
                              void* d_out, int out_size, void* d_ws, size_t ws_size,
                              hipStream_t stream) {
  const float* Hi  = (const float*)d_in[0];
  const float* Hj  = (const float*)d_in[1];
  const float* Wq  = (const float*)d_in[2];  const float* bq = (const float*)d_in[3];
  const float* Wk  = (const float*)d_in[4];  const float* bk = (const float*)d_in[5];
  const float* Wv  = (const float*)d_in[6];  const float* bv = (const float*)d_in[7];
  const float* lg  = (const float*)d_in[8];  const float* lt = (const float*)d_in[9];
  const float* e1  = (const float*)d_in[10]; const float* e2 = (const float*)d_in[11];
  const float* Wg  = (const float*)d_in[12]; const float* bg = (const float*)d_in[13];
  const float* g1  = (const float*)d_in[14]; const float* b1 = (const float*)d_in[15];
  const float* Wih = (const float*)d_in[16]; const float* Whh = (const float*)d_in[17];
  const float* bih = (const float*)d_in[18]; const float* bhh = (const float*)d_in[19];
  const float* g2  = (const float*)d_in[20]; const float* b2  = (const float*)d_in[21];
  float* out  = (float*)d_out;

  unsigned short* adph = (unsigned short*)d_ws;        // 128KB @ offset 0 (f16 adjacency)
  unsigned int* wg2 = (unsigned int*)d_ws + 32768;     // 8KB @ offset 128KB
  unsigned int* wq2 = (unsigned int*)d_ws + 65536;     // 3 x 8KB @ offset 256KB
  unsigned int* wk2 = wq2 + 2048;
  unsigned int* wv2 = wk2 + 2048;
  const size_t gi_off = 286720;                        // byte offset, 512-aligned
  const size_t gi_bytes = (size_t)2048 * TT * 192 * 2; // 96MB fp16
  const bool use_gi = ws_size >= gi_off + gi_bytes;
  unsigned int* GI2 = (unsigned int*)((char*)d_ws + gi_off);
  _Float16*     GIh = (_Float16*)((char*)d_ws + gi_off);

  k_prep<<<dim3(8),     dim3(256), 0, stream>>>(Wq, Wk, Wv, Wg, wq2, wk2, wv2, wg2);
  k_attn<<<dim3(BB*NN), dim3(256), 0, stream>>>(Hi, Hj, wq2, wk2, wv2, bq, bk, bv, lg, lt, out);
  k_adp <<<dim3(NN),    dim3(256), 0, stream>>>(e1, e2, adph);
  k_gcn <<<dim3(BB*TT), dim3(256), 0, stream>>>(out, adph, wg2, bg, g1, b1);
  if (use_gi) {
    k_gih   <<<dim3(BB*TT), dim3(256), 0, stream>>>(out, Wih, bih, GI2);
    k_gru_gi<<<dim3(512),   dim3(256), 0, stream>>>(out, GIh, Whh, bhh, g2, b2);
  } else {
    k_gru   <<<dim3(512),   dim3(256), 0, stream>>>(out, Wih, Whh, bih, bhh, g2, b2);
  }
}

// Round 7
// 447.320 us; speedup vs baseline: 2.3233x; 1.1661x over previous
//
#include <hip/hip_runtime.h>
#include <cstddef>

#define BB 8
#define TT 128
#define NN 256
#define DD 64

typedef _Float16 half2_t __attribute__((ext_vector_type(2)));
typedef _Float16 half4_t __attribute__((ext_vector_type(4)));
typedef _Float16 half8_t __attribute__((ext_vector_type(8)));
typedef float f32x4 __attribute__((ext_vector_type(4)));

#if defined(__has_builtin)
#  if __has_builtin(__builtin_amdgcn_fdot2)
#    define FDOT2(a,b,c) __builtin_amdgcn_fdot2((a),(b),(c),false)
#  endif
#endif
#ifndef FDOT2
#  define FDOT2(a,b,c) ((c) + (float)(a).x*(float)(b).x + (float)(a).y*(float)(b).y)
#endif

union h8u { half8_t v; half2_t h[4]; };

// wave64 sum via DPP row_shr tree (VALU-only; no DS-pipe waits)
__device__ __forceinline__ float wave64_sum(float x) {
#if defined(__has_builtin) && __has_builtin(__builtin_amdgcn_update_dpp)
  int t;
  t = __builtin_amdgcn_update_dpp(0, __builtin_bit_cast(int, x), 0x111, 0xF, 0xF, true);
  x += __builtin_bit_cast(float, t);
  t = __builtin_amdgcn_update_dpp(0, __builtin_bit_cast(int, x), 0x112, 0xF, 0xF, true);
  x += __builtin_bit_cast(float, t);
  t = __builtin_amdgcn_update_dpp(0, __builtin_bit_cast(int, x), 0x114, 0xF, 0xF, true);
  x += __builtin_bit_cast(float, t);
  t = __builtin_amdgcn_update_dpp(0, __builtin_bit_cast(int, x), 0x118, 0xF, 0xF, true);
  x += __builtin_bit_cast(float, t);
  float g0 = __builtin_bit_cast(float, __builtin_amdgcn_readlane(__builtin_bit_cast(int, x), 15));
  float g1 = __builtin_bit_cast(float, __builtin_amdgcn_readlane(__builtin_bit_cast(int, x), 31));
  float g2 = __builtin_bit_cast(float, __builtin_amdgcn_readlane(__builtin_bit_cast(int, x), 47));
  float g3 = __builtin_bit_cast(float, __builtin_amdgcn_readlane(__builtin_bit_cast(int, x), 63));
  return (g0 + g1) + (g2 + g3);
#else
  #pragma unroll
  for (int off = 32; off > 0; off >>= 1) x += __shfl_xor(x, off, 64);
  return x;
#endif
}

// ---------------- K0: pack W matrices to half2 in ws ----------------
__global__ __launch_bounds__(256) void k_prep(
    const float* __restrict__ Wq, const float* __restrict__ Wk, const float* __restrict__ Wv,
    const float* __restrict__ Wg, const float* __restrict__ Wih,
    unsigned int* __restrict__ wq2, unsigned int* __restrict__ wk2,
    unsigned int* __restrict__ wv2, unsigned int* __restrict__ wg2,
    unsigned int* __restrict__ wih2)
{
  int t = blockIdx.x * 256 + threadIdx.x;
  if (t < 2048) {
    half2_t a; a.x = (_Float16)Wq[2*t]; a.y = (_Float16)Wq[2*t+1];
    wq2[t] = __builtin_bit_cast(unsigned int, a);
    half2_t b; b.x = (_Float16)Wk[2*t]; b.y = (_Float16)Wk[2*t+1];
    wk2[t] = __builtin_bit_cast(unsigned int, b);
    half2_t c; c.x = (_Float16)Wv[2*t]; c.y = (_Float16)Wv[2*t+1];
    wv2[t] = __builtin_bit_cast(unsigned int, c);
    half2_t d; d.x = (_Float16)Wg[2*t]; d.y = (_Float16)Wg[2*t+1];
    wg2[t] = __builtin_bit_cast(unsigned int, d);
  }
  if (t < 6144) {
    half2_t h; h.x = (_Float16)Wih[2*t]; h.y = (_Float16)Wih[2*t+1];
    wih2[t] = __builtin_bit_cast(unsigned int, h);
  }
}

// ---------------- K1: MFMA fused QKV + per-(b,n) temporal attention ----------------
#define KSTR 72    // sK row stride (f16)
#define PSTR 136   // sVt / sP row stride (f16)

__device__ __forceinline__ half8_t wfrag(const unsigned int* __restrict__ W2, int e, int k0) {
  return *(const half8_t*)(W2 + e * 32 + (k0 >> 1));
}

__global__ __launch_bounds__(256, 2) void k_attn(
    const float* __restrict__ Hi, const float* __restrict__ Hj,
    const unsigned int* __restrict__ wq2, const unsigned int* __restrict__ wk2,
    const unsigned int* __restrict__ wv2,
    const float* __restrict__ bq, const float* __restrict__ bk, const float* __restrict__ bv,
    const float* __restrict__ lgp, const float* __restrict__ ltp,
    float* __restrict__ out)
{
  __shared__ __align__(16) _Float16 sK[TT][KSTR];
  __shared__ __align__(16) _Float16 sVt[DD][PSTR];
  __shared__ __align__(16) _Float16 sP[4][32][PSTR];
  __shared__ float sDecay[TT];

  const int b   = blockIdx.x >> 8;
  const int n   = blockIdx.x & 255;
  const int tid = threadIdx.x;
  const int w   = tid >> 6;
  const int l   = tid & 63;
  const int l16 = l & 15;
  const int lg4 = l >> 4;

  const float gamma = fmaxf(__expf(lgp[0]), 0.01f);
  const float tau   = fmaxf(__expf(ltp[0]), 0.01f);
  const float scale = 1.0f / (8.0f * tau);
  if (tid < TT) {
    float dt = gamma * (float)tid * (1.0f / 127.0f);
    sDecay[tid] = __logf(__expf(-dt) + 1e-8f);
  }

  const int row0 = 32 * w;
  half8_t hai[2][2], haj[2][2];
  #pragma unroll
  for (int mt = 0; mt < 2; mt++) {
    const int i = row0 + 16 * mt + l16;
    const float* ri = Hi + (((size_t)b * TT + i) * NN + n) * DD;
    const float* rj = Hj + (((size_t)b * TT + i) * NN + n) * DD;
    #pragma unroll
    for (int ks = 0; ks < 2; ks++) {
      const int k0 = 32 * ks + 8 * lg4;
      float4 a = *(const float4*)(ri + k0);
      float4 c = *(const float4*)(ri + k0 + 4);
      half8_t h;
      h[0]=(_Float16)a.x; h[1]=(_Float16)a.y; h[2]=(_Float16)a.z; h[3]=(_Float16)a.w;
      h[4]=(_Float16)c.x; h[5]=(_Float16)c.y; h[6]=(_Float16)c.z; h[7]=(_Float16)c.w;
      hai[mt][ks] = h;
      a = *(const float4*)(rj + k0);
      c = *(const float4*)(rj + k0 + 4);
      h[0]=(_Float16)a.x; h[1]=(_Float16)a.y; h[2]=(_Float16)a.z; h[3]=(_Float16)a.w;
      h[4]=(_Float16)c.x; h[5]=(_Float16)c.y; h[6]=(_Float16)c.z; h[7]=(_Float16)c.w;
      haj[mt][ks] = h;
    }
  }

  #pragma unroll
  for (int nt = 0; nt < 4; nt++) {
    const int e = 16 * nt + l16;
    half8_t wb0 = wfrag(wq2, e, 8 * lg4);
    half8_t wb1 = wfrag(wq2, e, 32 + 8 * lg4);
    const float be = bq[e];
    #pragma unroll
    for (int mt = 0; mt < 2; mt++) {
      f32x4 acc = {be, be, be, be};
      acc = __builtin_amdgcn_mfma_f32_16x16x32_f16(hai[mt][0], wb0, acc, 0, 0, 0);
      acc = __builtin_amdgcn_mfma_f32_16x16x32_f16(hai[mt][1], wb1, acc, 0, 0, 0);
      #pragma unroll
      for (int r = 0; r < 4; r++)
        sP[w][16 * mt + 4 * lg4 + r][e] = (_Float16)(acc[r] * scale);
    }
  }

  #pragma unroll
  for (int nt = 0; nt < 4; nt++) {
    const int e = 16 * nt + l16;
    half8_t wb0 = wfrag(wk2, e, 8 * lg4);
    half8_t wb1 = wfrag(wk2, e, 32 + 8 * lg4);
    const float be = bk[e];
    #pragma unroll
    for (int mt = 0; mt < 2; mt++) {
      f32x4 acc = {be, be, be, be};
      acc = __builtin_amdgcn_mfma_f32_16x16x32_f16(haj[mt][0], wb0, acc, 0, 0, 0);
      acc = __builtin_amdgcn_mfma_f32_16x16x32_f16(haj[mt][1], wb1, acc, 0, 0, 0);
      #pragma unroll
      for (int r = 0; r < 4; r++)
        sK[row0 + 16 * mt + 4 * lg4 + r][e] = (_Float16)acc[r];
    }
  }

  #pragma unroll
  for (int nt = 0; nt < 4; nt++) {
    const int e = 16 * nt + l16;
    half8_t wb0 = wfrag(wv2, e, 8 * lg4);
    half8_t wb1 = wfrag(wv2, e, 32 + 8 * lg4);
    const float be = bv[e];
    #pragma unroll
    for (int mt = 0; mt < 2; mt++) {
      f32x4 acc = {be, be, be, be};
      acc = __builtin_amdgcn_mfma_f32_16x16x32_f16(haj[mt][0], wb0, acc, 0, 0, 0);
      acc = __builtin_amdgcn_mfma_f32_16x16x32_f16(haj[mt][1], wb1, acc, 0, 0, 0);
      const int jb = row0 + 16 * mt + 4 * lg4;
      half4_t v4;
      v4[0] = (_Float16)acc[0]; v4[1] = (_Float16)acc[1];
      v4[2] = (_Float16)acc[2]; v4[3] = (_Float16)acc[3];
      *(half4_t*)(&sVt[e][jb]) = v4;
    }
  }
  __syncthreads();

  half8_t qa[2][2];
  #pragma unroll
  for (int mt = 0; mt < 2; mt++)
    #pragma unroll
    for (int ks = 0; ks < 2; ks++)
      qa[mt][ks] = *(const half8_t*)(&sP[w][16 * mt + l16][32 * ks + 8 * lg4]);

  float rs[2][4] = {{0.f,0.f,0.f,0.f},{0.f,0.f,0.f,0.f}};
  for (int jt = 0; jt < 8; jt++) {
    const int j = 16 * jt + l16;
    half8_t kb0 = *(const half8_t*)(&sK[j][8 * lg4]);
    half8_t kb1 = *(const half8_t*)(&sK[j][32 + 8 * lg4]);
    #pragma unroll
    for (int mt = 0; mt < 2; mt++) {
      f32x4 acc = {0.f, 0.f, 0.f, 0.f};
      acc = __builtin_amdgcn_mfma_f32_16x16x32_f16(qa[mt][0], kb0, acc, 0, 0, 0);
      acc = __builtin_amdgcn_mfma_f32_16x16x32_f16(qa[mt][1], kb1, acc, 0, 0, 0);
      #pragma unroll
      for (int r = 0; r < 4; r++) {
        const int il = 16 * mt + 4 * lg4 + r;
        int di = (row0 + il) - j; di = di < 0 ? -di : di;
        float p = __expf(acc[r] + sDecay[di]);
        rs[mt][r] += p;
        sP[w][il][j] = (_Float16)p;
      }
    }
  }

  f32x4 oacc[2][4] = {};
  #pragma unroll
  for (int ks = 0; ks < 4; ks++) {
    const int j0 = 32 * ks + 8 * lg4;
    half8_t pa0 = *(const half8_t*)(&sP[w][l16][j0]);
    half8_t pa1 = *(const half8_t*)(&sP[w][16 + l16][j0]);
    #pragma unroll
    for (int nt = 0; nt < 4; nt++) {
      half8_t vb = *(const half8_t*)(&sVt[16 * nt + l16][j0]);
      oacc[0][nt] = __builtin_amdgcn_mfma_f32_16x16x32_f16(pa0, vb, oacc[0][nt], 0, 0, 0);
      oacc[1][nt] = __builtin_amdgcn_mfma_f32_16x16x32_f16(pa1, vb, oacc[1][nt], 0, 0, 0);
    }
  }

  #pragma unroll
  for (int mt = 0; mt < 2; mt++)
    #pragma unroll
    for (int r = 0; r < 4; r++) {
      float v = rs[mt][r];
      v += __shfl_xor(v, 1, 64);
      v += __shfl_xor(v, 2, 64);
      v += __shfl_xor(v, 4, 64);
      v += __shfl_xor(v, 8, 64);
      rs[mt][r] = 1.0f / v;
    }
  #pragma unroll
  for (int mt = 0; mt < 2; mt++) {
    #pragma unroll
    for (int r = 0; r < 4; r++) {
      const int i = row0 + 16 * mt + 4 * lg4 + r;
      float* orow = out + (((size_t)b * TT + i) * NN + n) * DD;
      const float rl = rs[mt][r];
      #pragma unroll
      for (int nt = 0; nt < 4; nt++)
        orow[16 * nt + l16] = oacc[mt][nt][r] * rl;
    }
  }
}

// ---------------- K2: adjacency adph[m][n] = softmax_row_m(relu(e1@e2)) in f16 --------
__global__ __launch_bounds__(256) void k_adp(
    const float* __restrict__ e1, const float* __restrict__ e2,
    unsigned short* __restrict__ adph)
{
  const int m = blockIdx.x, n = threadIdx.x;
  float s = 0.f;
  #pragma unroll
  for (int k = 0; k < 32; k++) s += e1[m*32+k] * e2[k*256+n];
  s = fmaxf(s, 0.f);
  __shared__ float red[256];
  red[n] = s; __syncthreads();
  for (int off = 128; off > 0; off >>= 1) {
    if (n < off) red[n] = fmaxf(red[n], red[n+off]);
    __syncthreads();
  }
  float mx = red[0];
  __syncthreads();
  float p = __expf(s - mx);
  red[n] = p; __syncthreads();
  for (int off = 128; off > 0; off >>= 1) {
    if (n < off) red[n] += red[n+off];
    __syncthreads();
  }
  _Float16 h = (_Float16)(p / red[0]);
  adph[m*256 + n] = __builtin_bit_cast(unsigned short, h);
}

// ---------------- K3: MFMA GCN + residual + LN1 (in-place on x) ----------------
#define GSTR 280   // f16 row stride for sxhT / sgT (560 B, 16B-aligned)

__global__ __launch_bounds__(256, 2) void k_gcn(
    float* __restrict__ x, const unsigned short* __restrict__ adph,
    const unsigned int* __restrict__ wg2, const float* __restrict__ bg,
    const float* __restrict__ g1, const float* __restrict__ b1)
{
  __shared__ __align__(16) _Float16 sxhT[DD][GSTR];
  __shared__ __align__(16) _Float16 sgT[DD][GSTR];

  const int tid = threadIdx.x;
  const int w   = tid >> 6;
  const int l   = tid & 63;
  const int l16 = l & 15;
  const int lg4 = l >> 4;
  float* tile = x + (size_t)blockIdx.x * NN * DD;

  {
    const int d2 = tid & 31;
    const int mg = tid >> 5;
    #pragma unroll
    for (int it = 0; it < 16; it++) {
      const int m0 = mg * 2 + it * 16;
      float2 va = *(const float2*)(tile + (size_t)m0 * DD + 2 * d2);
      float2 vb = *(const float2*)(tile + (size_t)(m0 + 1) * DD + 2 * d2);
      half2_t h0; h0.x = (_Float16)va.x; h0.y = (_Float16)vb.x;
      half2_t h1; h1.x = (_Float16)va.y; h1.y = (_Float16)vb.y;
      *(half2_t*)(&sxhT[2 * d2][m0])     = h0;
      *(half2_t*)(&sxhT[2 * d2 + 1][m0]) = h1;
    }
  }
  __syncthreads();

  f32x4 acc1[4][4] = {};
  for (int ks = 0; ks < 8; ks++) {
    const int k0 = 32 * ks + 8 * lg4;
    half8_t bfr[4], afr[4];
    #pragma unroll
    for (int nt = 0; nt < 4; nt++)
      bfr[nt] = *(const half8_t*)(&sxhT[16 * nt + l16][k0]);
    #pragma unroll
    for (int mt = 0; mt < 4; mt++) {
      const int m = 64 * w + 16 * mt + l16;
      afr[mt] = *(const half8_t*)(adph + m * 256 + k0);
    }
    #pragma unroll
    for (int mt = 0; mt < 4; mt++)
      #pragma unroll
      for (int nt = 0; nt < 4; nt++)
        acc1[mt][nt] = __builtin_amdgcn_mfma_f32_16x16x32_f16(afr[mt], bfr[nt], acc1[mt][nt], 0, 0, 0);
  }

  #pragma unroll
  for (int mt = 0; mt < 4; mt++)
    #pragma unroll
    for (int nt = 0; nt < 4; nt++) {
      half4_t g4;
      g4[0] = (_Float16)acc1[mt][nt][0]; g4[1] = (_Float16)acc1[mt][nt][1];
      g4[2] = (_Float16)acc1[mt][nt][2]; g4[3] = (_Float16)acc1[mt][nt][3];
      *(half4_t*)(&sgT[16 * nt + l16][64 * w + 16 * mt + 4 * lg4]) = g4;
    }
  __syncthreads();

  half8_t wb[4][2];
  float bgv[4], g1v[4], b1v[4];
  #pragma unroll
  for (int et = 0; et < 4; et++) {
    const int e = 16 * et + l16;
    wb[et][0] = wfrag(wg2, e, 8 * lg4);
    wb[et][1] = wfrag(wg2, e, 32 + 8 * lg4);
    bgv[et] = bg[e]; g1v[et] = g1[e]; b1v[et] = b1[e];
  }

  #pragma unroll 1
  for (int mt = 0; mt < 4; mt++) {
    half8_t ga[2];
    #pragma unroll
    for (int ks = 0; ks < 2; ks++) {
      half8_t h;
      #pragma unroll
      for (int j = 0; j < 8; j++)
        h[j] = sgT[32 * ks + 8 * lg4 + j][64 * w + 16 * mt + l16];
      ga[ks] = h;
    }
    f32x4 acc2[4];
    #pragma unroll
    for (int et = 0; et < 4; et++) {
      f32x4 a = {bgv[et], bgv[et], bgv[et], bgv[et]};
      a = __builtin_amdgcn_mfma_f32_16x16x32_f16(ga[0], wb[et][0], a, 0, 0, 0);
      a = __builtin_amdgcn_mfma_f32_16x16x32_f16(ga[1], wb[et][1], a, 0, 0, 0);
      acc2[et] = a;
    }
    #pragma unroll
    for (int r = 0; r < 4; r++) {
      const int mrow = 64 * w + 16 * mt + 4 * lg4 + r;
      float* xr = tile + (size_t)mrow * DD;
      float y[4], s1 = 0.f, s2 = 0.f;
      #pragma unroll
      for (int et = 0; et < 4; et++) {
        float h = fmaxf(acc2[et][r], 0.f);
        float yv = xr[16 * et + l16] + h;
        y[et] = yv; s1 += yv; s2 += yv * yv;
      }
      #pragma unroll
      for (int off = 1; off < 16; off <<= 1) {
        s1 += __shfl_xor(s1, off, 64);
        s2 += __shfl_xor(s2, off, 64);
      }
      const float mean = s1 * (1.f / 64.f);
      const float var  = fmaxf(s2 * (1.f / 64.f) - mean * mean, 0.f);
      const float rstd = rsqrtf(var + 1e-5f);
      #pragma unroll
      for (int et = 0; et < 4; et++)
        xr[16 * et + l16] = (y[et] - mean) * rstd * g1v[et] + b1v[et];
    }
  }
}

// ---------------- K3b: MFMA GI = x_ln1 @ Wih^T + bih (f16 out, no LDS) ----------
// One block = one (b,t). 4 waves; wave w owns n in [64w, 64w+64).
// A = Wih (rows e, f16-packed), B = x rows as cols. C/D: row=e-local (4 consecutive
// per lane -> single half4 store), col=n-local.
__global__ __launch_bounds__(256, 4) void k_gih(
    const float* __restrict__ x, const unsigned int* __restrict__ wih2,
    const float* __restrict__ bih, _Float16* __restrict__ GIh)
{
  const int tid = threadIdx.x;
  const int w   = tid >> 6;
  const int l   = tid & 63;
  const int l16 = l & 15;
  const int lg4 = l >> 4;
  const int b = blockIdx.x >> 7, t = blockIdx.x & 127;

  // B-frags: x rows (cvt f32->f16)
  half8_t xb[4][2];
  #pragma unroll
  for (int nt = 0; nt < 4; nt++) {
    const int n = 64 * w + 16 * nt + l16;
    const float* xr = x + (((size_t)b * TT + t) * NN + n) * DD;
    #pragma unroll
    for (int ks = 0; ks < 2; ks++) {
      const int k0 = 32 * ks + 8 * lg4;
      float4 a = *(const float4*)(xr + k0);
      float4 c = *(const float4*)(xr + k0 + 4);
      half8_t h;
      h[0]=(_Float16)a.x; h[1]=(_Float16)a.y; h[2]=(_Float16)a.z; h[3]=(_Float16)a.w;
      h[4]=(_Float16)c.x; h[5]=(_Float16)c.y; h[6]=(_Float16)c.z; h[7]=(_Float16)c.w;
      xb[nt][ks] = h;
    }
  }

  _Float16* gout = GIh + ((size_t)t * 2048 + b * 256 + 64 * w) * 192;

  #pragma unroll 4
  for (int et = 0; et < 12; et++) {
    half8_t wa0 = wfrag(wih2, 16 * et + l16, 8 * lg4);
    half8_t wa1 = wfrag(wih2, 16 * et + l16, 32 + 8 * lg4);
    float4 bb = *(const float4*)(bih + 16 * et + 4 * lg4);
    #pragma unroll
    for (int nt = 0; nt < 4; nt++) {
      f32x4 acc = {bb.x, bb.y, bb.z, bb.w};
      acc = __builtin_amdgcn_mfma_f32_16x16x32_f16(wa0, xb[nt][0], acc, 0, 0, 0);
      acc = __builtin_amdgcn_mfma_f32_16x16x32_f16(wa1, xb[nt][1], acc, 0, 0, 0);
      half4_t o;
      o[0] = (_Float16)acc[0]; o[1] = (_Float16)acc[1];
      o[2] = (_Float16)acc[2]; o[3] = (_Float16)acc[3];
      *(half4_t*)(gout + (size_t)(16 * nt + l16) * 192 + 16 * et + 4 * lg4) = o;
    }
  }
}

// ---------------- K4: GRU over T, wave-per-sequence (DPP LN, 1 shfl/t) ----------
__global__ __launch_bounds__(256, 2) void k_gru_gi(
    float* __restrict__ x, const _Float16* __restrict__ GIh,
    const float* __restrict__ Whh, const float* __restrict__ bhh,
    const float* __restrict__ g2, const float* __restrict__ b2)
{
  const int tid = threadIdx.x;
  const int w = tid >> 6;
  const int l = tid & 63;
  const int b = blockIdx.x >> 6, n4 = blockIdx.x & 63;

  half2_t wr[32], wz[32], wn[32];
  {
    float2 tmp[32];
    const float2* W0 = (const float2*)(Whh + (size_t)l * 64);
    #pragma unroll
    for (int q = 0; q < 32; q++) tmp[q] = W0[q];
    #pragma unroll
    for (int k = 0; k < 32; k++) {
      float lo = (k & 1) ? tmp[k >> 1].y : tmp[k >> 1].x;
      float hi = (k & 1) ? tmp[16 + (k >> 1)].y : tmp[16 + (k >> 1)].x;
      half2_t h; h.x = (_Float16)lo; h.y = (_Float16)hi; wr[k] = h;
    }
    const float2* W1 = (const float2*)(Whh + (size_t)(64 + l) * 64);
    #pragma unroll
    for (int q = 0; q < 32; q++) tmp[q] = W1[q];
    #pragma unroll
    for (int k = 0; k < 32; k++) {
      float lo = (k & 1) ? tmp[k >> 1].y : tmp[k >> 1].x;
      float hi = (k & 1) ? tmp[16 + (k >> 1)].y : tmp[16 + (k >> 1)].x;
      half2_t h; h.x = (_Float16)lo; h.y = (_Float16)hi; wz[k] = h;
    }
    const float2* W2 = (const float2*)(Whh + (size_t)(128 + l) * 64);
    #pragma unroll
    for (int q = 0; q < 32; q++) tmp[q] = W2[q];
    #pragma unroll
    for (int k = 0; k < 32; k++) {
      float lo = (k & 1) ? tmp[k >> 1].y : tmp[k >> 1].x;
      float hi = (k & 1) ? tmp[16 + (k >> 1)].y : tmp[16 + (k >> 1)].x;
      half2_t h; h.x = (_Float16)lo; h.y = (_Float16)hi; wn[k] = h;
    }
  }
  const float bhr = bhh[l], bhz = bhh[64 + l], bhn = bhh[128 + l];
  const float lng = g2[l], lnb = b2[l];

  float hreg = 0.f;
  unsigned int h2pack = 0;   // (h[k], h[k+32]) f16 pair in lane k<32

  const size_t gistride = (size_t)2048 * 192;
  const size_t xstride  = (size_t)NN * DD;
  size_t gioff = ((size_t)b * 256 + n4 * 4 + w) * 192 + l;
  size_t xoff  = (((size_t)b * TT) * NN + n4 * 4 + w) * DD + l;

  float gir = (float)GIh[gioff];
  float giz = (float)GIh[gioff + 64];
  float gin = (float)GIh[gioff + 128];
  float xv  = x[xoff];

  for (int t = 0; t < TT; t++) {
    const size_t adv = (t + 1 < TT) ? 1 : 0;
    const size_t gioff_n = gioff + adv * gistride;
    const size_t xoff_n  = xoff  + adv * xstride;
    float gir_n = (float)GIh[gioff_n];
    float giz_n = (float)GIh[gioff_n + 64];
    float gin_n = (float)GIh[gioff_n + 128];
    float xv_n  = x[xoff_n];

    float ar = bhr, az = bhz, an = bhn;
    #pragma unroll
    for (int k = 0; k < 32; k++) {
      half2_t s2 = __builtin_bit_cast(half2_t,
                     __builtin_amdgcn_readlane((int)h2pack, k));
      ar = FDOT2(wr[k], s2, ar);
      az = FDOT2(wz[k], s2, az);
      an = FDOT2(wn[k], s2, an);
    }

    const float r = 1.f / (1.f + __expf(-(gir + ar)));
    const float z = 1.f / (1.f + __expf(-(giz + az)));
    const float e = __expf(2.f * (gin + r * an));
    const float nt = 1.f - 2.f / (e + 1.f);
    const float hn = (1.f - z) * nt + z * hreg;
    hreg = hn;

    const float other = __shfl_xor(hn, 32, 64);
    const float plo = (l < 32) ? hn : other;
    const float phi = (l < 32) ? other : hn;
    half2_t hp; hp.x = (_Float16)plo; hp.y = (_Float16)phi;
    h2pack = __builtin_bit_cast(unsigned int, hp);

    const float yv = xv + hn;
    const float s1  = wave64_sum(yv);
    const float s2v = wave64_sum(yv * yv);
    const float mean = s1 * 0.015625f;
    const float var  = fmaxf(s2v * 0.015625f - mean * mean, 0.f);
    const float hm = (yv - mean) * rsqrtf(var + 1e-5f) * lng + lnb;
    x[xoff] = xv + hm;

    gir = gir_n; giz = giz_n; gin = gin_n; xv = xv_n;
    gioff += gistride; xoff += xstride;
  }
}

// ---------------- K4 fallback: original fused GRU (ws too small for GI) ----------------
__global__ __launch_bounds__(256) void k_gru(
    float* __restrict__ x,
    const float* __restrict__ Wih, const float* __restrict__ Whh,
    const float* __restrict__ bih, const float* __restrict__ bhh,
    const float* __restrict__ g2, const float* __restrict__ b2)
{
  __shared__ half2_t sWi[192][33];
  __shared__ half2_t sWh[192][33];
  __shared__ float   xs[4][64];
  __shared__ half2_t xs_h[4][32];
  __shared__ float   hs_f[4][64];
  __shared__ half2_t hs_h[4][32];
  __shared__ float   gis[4][192];
  __shared__ float   ghs[4][192];

  const int b  = blockIdx.x >> 6;
  const int ng = blockIdx.x & 63;

  for (int idx = threadIdx.x; idx < 192 * 32; idx += 256) {
    int g = idx >> 5, dh = idx & 31;
    half2_t hv; hv.x = (_Float16)Wih[g*64 + 2*dh]; hv.y = (_Float16)Wih[g*64 + 2*dh + 1];
    sWi[g][dh] = hv;
    half2_t hw; hw.x = (_Float16)Whh[g*64 + 2*dh]; hw.y = (_Float16)Whh[g*64 + 2*dh + 1];
    sWh[g][dh] = hw;
  }
  const int s_d = threadIdx.x >> 6;
  const int d_d = threadIdx.x & 63;
  hs_f[s_d][d_d] = 0.f;
  ((_Float16*)hs_h[s_d])[d_d] = (_Float16)0.f;
  const float lng = g2[d_d], lnb = b2[d_d];

  int   tsk_s[3], tsk_g[3];
  float tb_i[3], tb_h[3];
  #pragma unroll
  for (int k = 0; k < 3; k++) {
    int task = threadIdx.x + k * 256;
    tsk_s[k] = task / 192; tsk_g[k] = task % 192;
    tb_i[k] = bih[tsk_g[k]]; tb_h[k] = bhh[tsk_g[k]];
  }
  __syncthreads();

  const size_t base = (((size_t)b * TT) * NN + ng * 4) * DD;
  for (int t = 0; t < TT; t++) {
    const size_t row = base + (size_t)t * NN * DD + s_d * 64 + d_d;
    float xv = x[row];
    xs[s_d][d_d] = xv;
    ((_Float16*)xs_h[s_d])[d_d] = (_Float16)xv;
    __syncthreads();

    #pragma unroll
    for (int k = 0; k < 3; k++) {
      int s = tsk_s[k], g = tsk_g[k];
      float ai = tb_i[k], ah = tb_h[k];
      #pragma unroll
      for (int dh = 0; dh < 32; dh++) {
        ai = FDOT2(sWi[g][dh], xs_h[s][dh], ai);
        ah = FDOT2(sWh[g][dh], hs_h[s][dh], ah);
      }
      gis[s][g] = ai; ghs[s][g] = ah;
    }
    __syncthreads();

    float gr = gis[s_d][d_d]      + ghs[s_d][d_d];
    float gz = gis[s_d][64 + d_d] + ghs[s_d][64 + d_d];
    float r  = 1.f / (1.f + __expf(-gr));
    float z  = 1.f / (1.f + __expf(-gz));
    float nn = tanhf(gis[s_d][128 + d_d] + r * ghs[s_d][128 + d_d]);
    float ho = hs_f[s_d][d_d];
    float hn = (1.f - z) * nn + z * ho;

    float yv = xs[s_d][d_d] + hn;
    float s1 = yv, s2 = yv * yv;
    #pragma unroll
    for (int off = 32; off > 0; off >>= 1) {
      s1 += __shfl_xor(s1, off, 64);
      s2 += __shfl_xor(s2, off, 64);
    }
    float mean = s1 * (1.f / 64.f);
    float var  = fmaxf(s2 * (1.f / 64.f) - mean * mean, 0.f);
    float hm = (yv - mean) * rsqrtf(var + 1e-5f) * lng + lnb;

    x[row] = xs[s_d][d_d] + hm;
    hs_f[s_d][d_d] = hn;
    ((_Float16*)hs_h[s_d])[d_d] = (_Float16)hn;
    __syncthreads();
  }
}

extern "C" void kernel_launch(void* const* d_in, const int* in_sizes, int n_in,
                              void* d_out, int out_size, void* d_ws, size_t ws_size,
                              hipStream_t stream) {
  const float* Hi  = (const float*)d_in[0];
  const float* Hj  = (const float*)d_in[1];
  const float* Wq  = (const float*)d_in[2];  const float* bq = (const float*)d_in[3];
  const float* Wk  = (const float*)d_in[4];  const float* bk = (const float*)d_in[5];
  const float* Wv  = (const float*)d_in[6];  const float* bv = (const float*)d_in[7];
  const float* lg  = (const float*)d_in[8];  const float* lt = (const float*)d_in[9];
  const float* e1  = (const float*)d_in[10]; const float* e2 = (const float*)d_in[11];
  const float* Wg  = (const float*)d_in[12]; const float* bg = (const float*)d_in[13];
  const float* g1  = (const float*)d_in[14]; const float* b1 = (const float*)d_in[15];
  const float* Wih = (const float*)d_in[16]; const float* Whh = (const float*)d_in[17];
  const float* bih = (const float*)d_in[18]; const float* bhh = (const float*)d_in[19];
  const float* g2  = (const float*)d_in[20]; const float* b2  = (const float*)d_in[21];
  float* out  = (float*)d_out;

  unsigned short* adph = (unsigned short*)d_ws;        // 128KB @ offset 0 (f16 adjacency)
  unsigned int* wg2  = (unsigned int*)d_ws + 32768;    // 8KB  @ byte 131072
  unsigned int* wq2  = (unsigned int*)d_ws + 65536;    // 3 x 8KB @ byte 262144
  unsigned int* wk2  = wq2 + 2048;
  unsigned int* wv2  = wk2 + 2048;
  unsigned int* wih2 = (unsigned int*)d_ws + 71680;    // 24KB @ byte 286720
  const size_t gi_off = 311296;                        // byte offset, 512-aligned
  const size_t gi_bytes = (size_t)2048 * TT * 192 * 2; // ~96MB fp16
  const bool use_gi = ws_size >= gi_off + gi_bytes;
  _Float16* GIh = (_Float16*)((char*)d_ws + gi_off);

  k_prep<<<dim3(24),    dim3(256), 0, stream>>>(Wq, Wk, Wv, Wg, Wih, wq2, wk2, wv2, wg2, wih2);
  k_attn<<<dim3(BB*NN), dim3(256), 0, stream>>>(Hi, Hj, wq2, wk2, wv2, bq, bk, bv, lg, lt, out);
  k_adp <<<dim3(NN),    dim3(256), 0, stream>>>(e1, e2, adph);
  k_gcn <<<dim3(BB*TT), dim3(256), 0, stream>>>(out, adph, wg2, bg, g1, b1);
  if (use_gi) {
    k_gih   <<<dim3(BB*TT), dim3(256), 0, stream>>>(out, wih2, bih, GIh);
    k_gru_gi<<<dim3(512),   dim3(256), 0, stream>>>(out, GIh, Whh, bhh, g2, b2);
  } else {
    k_gru   <<<dim3(512),   dim3(256), 0, stream>>>(out, Wih, Whh, bih, bhh, g2, b2);
  }
}